// Round 10
// baseline (586.541 us; speedup 1.0000x reference)
//
#include <hip/hip_runtime.h>
#include <hip/hip_bf16.h>

// B=64 (LSTM time axis via torch batch_first quirk), L=64 (only col 63 used),
// N=256, C=8, Ct=4 -> NQ=1024 sequences, H=128, 4H=512, RH1=128, RH2=64, S=4.
//
// All matmuls use STACKED split-bf16 MFMA: f = hi + lo (two bf16); stack
// [A_hi|A_lo] along K against [B_hi;B_lo] in fp32 accum (~2^-17 rel error).
//
// R10: LSTM MFMAs are inline asm consuming the weight B-frags DIRECTLY from
// AGPRs ("a" constraint) -- with the hazard wait-states the compiler cannot
// insert around INLINEASM done manually: s_nop 3 before the first MFMA of a
// chain (VALU acc-init -> MFMA SrcC window) and s_nop 7 x2 after the last
// (MFMA D-write -> VALU read window). R8 proved the no-nop version corrupts;
// R9 proved the builtin path burns ~290 cyc/step on v_accvgpr_read copies.

typedef __attribute__((ext_vector_type(8))) short short8;   // 8 bf16 in 4 VGPRs
typedef __attribute__((ext_vector_type(4))) float f32x4;

#define MFMA16(a, b, c) __builtin_amdgcn_mfma_f32_16x16x32_bf16(a, b, c, 0, 0, 0)

// Direct-AGPR MFMA chain ops (LSTM inner loop only). Nops ride inside the
// dataflow-ordered asm so the scheduler cannot hoist acc readers above them.
#define MFMA_FIRST(accv, av, bv) \
    asm("s_nop 3\n\tv_mfma_f32_16x16x32_bf16 %0, %1, %2, %0" \
        : "+v"(accv) : "v"(av), "a"(bv))
#define MFMA_MID(accv, av, bv) \
    asm("v_mfma_f32_16x16x32_bf16 %0, %1, %2, %0" \
        : "+v"(accv) : "v"(av), "a"(bv))
#define MFMA_LAST(accv, av, bv) \
    asm("v_mfma_f32_16x16x32_bf16 %0, %1, %2, %0\n\ts_nop 7\n\ts_nop 7" \
        : "+v"(accv) : "v"(av), "a"(bv))

__device__ __forceinline__ float sigf(float x)   { return 1.0f / (1.0f + __expf(-x)); }
__device__ __forceinline__ float tanh_f(float x) { return 1.0f - 2.0f / (__expf(2.0f * x) + 1.0f); }

__device__ __forceinline__ ushort bf16_rne(float v) {
    unsigned u = __float_as_uint(v);
    return (ushort)((u + 0x7FFFu + ((u >> 16) & 1u)) >> 16);
}
__device__ __forceinline__ void bsplit(float v, ushort& h, ushort& l) {
    h = bf16_rne(v);
    float fh = __uint_as_float(((unsigned)h) << 16);
    l = bf16_rne(v - fh);
}

// ---------------- init: cur(hi/lo) <- x[:, 63, :, :] ----------------
__global__ void init_cur_k(const float* __restrict__ x,
                           ushort* __restrict__ cur_hi, ushort* __restrict__ cur_lo)
{
    int i   = blockIdx.x * 256 + threadIdx.x;   // 0 .. 524287
    int b   = i >> 13;
    int rem = i & 8191;
    ushort h, l; bsplit(x[(size_t)b * 524288 + 63 * 8192 + rem], h, l);
    cur_hi[i] = h; cur_lo[i] = l;
}

// ---------------- split hidden_intensity to bf16 hi/lo, once ----------------
__global__ void split_hi_k(const float* __restrict__ hi,
                           ushort* __restrict__ hi_hi, ushort* __restrict__ hi_lo)
{
    int i = blockIdx.x * 256 + threadIdx.x;     // 0 .. 2097151
    ushort h, l; bsplit(hi[i], h, l);
    hi_hi[i] = h; hi_lo[i] = l;
}

// ---------------- pack W1/W2/W3 into stacked-K MFMA B-frags, once ------------
// B-frag (16x16x32): lane l holds B[k = (l>>4)*8 + j][col = l&15], j=0..7.
__global__ void pack_w_k(const float* __restrict__ W1, const float* __restrict__ W2,
                         const float* __restrict__ W3, ushort* __restrict__ wp1,
                         ushort* __restrict__ wp2, ushort* __restrict__ wp3)
{
    int i = blockIdx.x * 256 + threadIdx.x;
    if (i < 65536) {                       // wp1 [kt16][nt8][512]; K'=512 over [hs|hi]
        int fragid = i >> 9, lj = i & 511;
        int kt = fragid >> 3, nt = fragid & 7;
        int l = lj >> 3, j = lj & 7;
        int klocal = (l >> 4) * 8 + j;
        int k = (kt >> 3) * 128 + (kt & 3) * 32 + klocal;   // source k (0..255)
        int hsel = (kt >> 2) & 1;
        int o = nt * 16 + (l & 15);
        ushort h, lo; bsplit(W1[o * 257 + k], h, lo);
        wp1[i] = hsel ? lo : h;
    } else if (i < 65536 + 16384) {        // wp2 [kt8][nt4][512]; K'=256
        int ii = i - 65536;
        int fragid = ii >> 9, lj = ii & 511;
        int kt = fragid >> 2, nt = fragid & 3;
        int l = lj >> 3, j = lj & 7;
        int klocal = (l >> 4) * 8 + j;
        int k = (kt & 3) * 32 + klocal;                     // 0..127
        int hsel = (kt >> 2) & 1;
        int o = nt * 16 + (l & 15);
        ushort h, lo; bsplit(W2[o * 128 + k], h, lo);
        wp2[ii] = hsel ? lo : h;
    } else if (i < 65536 + 16384 + 2048) { // wp3 [kt4][512]; K'=128
        int ii = i - 65536 - 16384;
        int kt = ii >> 9, lj = ii & 511;
        int l = lj >> 3, j = lj & 7;
        int klocal = (l >> 4) * 8 + j;
        int k = (kt & 1) * 32 + klocal;                     // 0..63
        int hsel = kt >> 1;
        int c = l & 15;
        float v = (c < 8) ? W3[c * 64 + k] : 0.0f;
        ushort h, lo; bsplit(v, h, lo);
        wp3[ii] = hsel ? lo : h;
    }
}

// ---------------- pack [W_hh(stacked) | W_ih(stacked)] B-frags, once ---------
// wpB [kt(9)][ntile(32)][512]: kt 0..3 = Whh_hi, 4..7 = Whh_lo, 8 = x-plane
// ([Wih_hi(8)|Wih_lo(8)|0(16)]). col = ntile*16 + (l&15) = gate row 0..511.
__global__ void pack_wB_k(const float* __restrict__ W_hh, const float* __restrict__ W_ih,
                          ushort* __restrict__ wpB)
{
    int i = blockIdx.x * 256 + threadIdx.x;     // 0 .. 147455
    if (i >= 147456) return;
    int frag = i >> 9, lj = i & 511;
    int kt = frag >> 5, ntile = frag & 31;
    int l = lj >> 3, j = lj & 7;
    int klocal = (l >> 4) * 8 + j;              // 0..31
    int col = ntile * 16 + (l & 15);            // gate row 0..511
    float v; int hsel;
    if (kt < 8) {
        int k = (kt & 3) * 32 + klocal;
        hsel = kt >> 2;
        v = W_hh[col * 128 + k];
    } else {
        if (klocal < 8)       { v = W_ih[col * 8 + klocal];       hsel = 0; }
        else if (klocal < 16) { v = W_ih[col * 8 + (klocal - 8)]; hsel = 1; }
        else                  { v = 0.0f;                          hsel = 0; }
    }
    ushort h, lo; bsplit(v, h, lo);
    wpB[i] = hsel ? lo : h;
}

// ---------------- LSTM scan: stacked split-bf16 MFMA, 256 blocks ------------
// 256 wgs x 512 thr (8 waves = col-groups). wg owns 4 sequences at M-rows
// {0,4,8,12}. Wave cg computes gate cols g*128 + cg*16 + (l&15), g=0..3.
// C-reg 0 of lane (lk,li) = preact of item (seq=lk, col=cg*16+li).
// Weight frags pinned in AGPRs; MFMAs consume them directly via "a"-operand
// inline asm with manual hazard nops. hs dump block-coalesced from LDS zone.
// In-loop barrier drains lgkmcnt only (global stores stay in flight).
__global__ __launch_bounds__(512, 2) void lstm_mfma_k(
    const ushort* __restrict__ cur_hi, const ushort* __restrict__ cur_lo,
    const ushort* __restrict__ wpB, const float* __restrict__ b_ih,
    const float* __restrict__ b_hh, ushort* __restrict__ hs_hi,
    ushort* __restrict__ hs_lo)
{
    __shared__ __align__(16) ushort zone[2][8][640];   // 20 KB

    const int t  = threadIdx.x;
    const int cg = t >> 6, l = t & 63;
    const int li = l & 15, lk = l >> 4;
    const int q0 = blockIdx.x * 4;

    // B-frags: 4 gates x 9 kt planes (8 h + 1 x) = 144 regs -> pinned AGPRs
    short8 bw[4][9];
#pragma unroll
    for (int g = 0; g < 4; ++g)
#pragma unroll
        for (int kt = 0; kt < 9; ++kt) {
            bw[g][kt] = *(const short8*)(wpB + (size_t)(kt * 32 + g * 8 + cg) * 512 + l * 8);
            asm volatile("" : "+a"(bw[g][kt]));   // pin to AGPR class, no remat
        }

    float bsum[4];
#pragma unroll
    for (int g = 0; g < 4; ++g) {
        int gc = g * 128 + cg * 16 + li;
        bsum[g] = b_ih[gc] + b_hh[gc];
    }

    for (int i = t; i < 5120; i += 512) ((uint*)zone)[i] = 0;   // both bufs = 0
    float cc = 0.0f;
    __syncthreads();

    const int zp_hi = cg >> 1, zp_lo = 4 + (cg >> 1);
    const int jl    = (cg & 1) * 16 + li;
    const int roff  = li * 40 + lk * 8;       // A-frag read offset in a plane
    const int srow  = lk * 4;                 // this lane's item row (seq lk)

    // branchless per-lane x source: lk=0 -> x_hi, lk=1 -> x_lo, lk>=2 -> any
    // finite garbage (pairs with ZERO rows of the x B-plane -> contributes 0).
    const ushort* xsrc = (lk == 0) ? cur_hi : ((lk == 1) ? cur_lo : cur_hi);
    const size_t  xoff = (size_t)(q0 + (li >> 2)) * 8;

    // coalesced-dump indices: thread t covers 2 ushorts of the 2KB step chunk
    const int dtt  = t & 255;
    const int dseq = dtt >> 6;                 // 0..3
    const int dcol = (dtt << 1) & 127;         // even col
    const int dsel = t >> 8;                   // 0 = hi, 1 = lo
    const ushort* dzsrc0 = &zone[0][(dcol >> 5) + dsel * 4][dseq * 160 + (dcol & 31)];
    const ushort* dzsrc1 = &zone[1][(dcol >> 5) + dsel * 4][dseq * 160 + (dcol & 31)];
    ushort* ddst = (dsel ? hs_lo : hs_hi) + (size_t)(q0 + dseq) * 128 + dcol;

    auto dostep = [&](int step, int p) {
        const int pn = p ^ 1;
        // x A-frag load issued first; L2 latency hides under the LDS reads
        short8 xa = *(const short8*)(xsrc + (size_t)step * 8192 + xoff);

        short8 ah[8];
#pragma unroll
        for (int kt = 0; kt < 8; ++kt)
            ah[kt] = *(const short8*)&zone[p][kt][roff];

        f32x4 acc[4];
#pragma unroll
        for (int g = 0; g < 4; ++g)
            acc[g] = (f32x4){bsum[g], bsum[g], bsum[g], bsum[g]};

        // chains: kt0 first (s_nop prefix), kt1..7 mid, x-plane last (s_nop tail)
#pragma unroll
        for (int g = 0; g < 4; ++g)
            MFMA_FIRST(acc[g], ah[0], bw[g][0]);
#pragma unroll
        for (int kt = 1; kt < 8; ++kt)
#pragma unroll
            for (int g = 0; g < 4; ++g)
                MFMA_MID(acc[g], ah[kt], bw[g][kt]);
#pragma unroll
        for (int g = 0; g < 4; ++g)
            MFMA_LAST(acc[g], xa, bw[g][8]);

        // gate math (torch order i,f,g,o): ONE packed item per lane (reg 0)
        float pi = acc[0][0], pf = acc[1][0], pg = acc[2][0], po = acc[3][0];
        cc = sigf(pf) * cc + sigf(pi) * tanh_f(pg);
        float hv = sigf(po) * tanh_f(cc);
        ushort hh, hl; bsplit(hv, hh, hl);
        zone[pn][zp_hi][srow * 40 + jl] = hh;
        zone[pn][zp_lo][srow * 40 + jl] = hl;
        // drain LDS only; global loads/stores stay in flight
        asm volatile("s_waitcnt lgkmcnt(0)\n\ts_barrier" ::: "memory");

        // block-coalesced dump of zone[pn] (h after this step) -> hs.
        // Reads are covered by the NEXT step's lgkmcnt(0)+barrier, and
        // zone[pn] is not rewritten until step+2. Store is fire-and-forget.
        uint v = *(const uint*)(pn ? dzsrc1 : dzsrc0);
        *(uint*)(ddst + (size_t)step * 131072) = v;
    };

    for (int s2 = 0; s2 < 32; ++s2) {
        dostep(s2 * 2,     0);
        dostep(s2 * 2 + 1, 1);
    }
}

// ---------------- MLP + head for one roll: stacked split-bf16 MFMA ----------
// 1024 wgs (b x 16 q-groups) x 256 thr (4 waves). wg owns 64 items (M=64).
__global__ __launch_bounds__(256, 2) void mlp_mfma_k(
    const ushort* __restrict__ hs_hi, const ushort* __restrict__ hs_lo,
    const ushort* __restrict__ hi_hi, const ushort* __restrict__ hi_lo,
    const float* __restrict__ r, int jstep,
    const ushort* __restrict__ wp1, const ushort* __restrict__ wp2,
    const ushort* __restrict__ wp3,
    const float* __restrict__ W1, const float* __restrict__ b1,
    const float* __restrict__ b2, const float* __restrict__ b3,
    const float* __restrict__ Wf, const float* __restrict__ bfp,
    ushort* __restrict__ cur_hi, ushort* __restrict__ cur_lo,
    float* __restrict__ out)
{
    __shared__ __align__(16) ushort h1f[8 * 4 * 640];   // [plane8][mt4][16x40]  40KB
    __shared__ __align__(16) ushort h2f[4 * 4 * 640];   // [plane4][mt4][16x40]  20KB

    const int t = threadIdx.x;
    const int w = t >> 6, l = t & 63;
    const int lrow = l & 15, lk = l >> 4;
    const int b = blockIdx.x >> 4;
    const int qb = (blockIdx.x & 15) * 64;
    const float rb = r[b * 4 + jstep];

    // ============ GEMM1: h1 = relu([hs|hi|r] @ W1^T + b1), K'=512 ============
    f32x4 acc[4][2];
#pragma unroll
    for (int nt = 0; nt < 2; ++nt) {
        int col = w * 32 + nt * 16 + lrow;
        float bias = b1[col] + rb * W1[col * 257 + 256];   // fold r-col + b1 (fp32)
#pragma unroll
        for (int mt = 0; mt < 4; ++mt)
            acc[mt][nt] = (f32x4){bias, bias, bias, bias};
    }

#pragma unroll 4
    for (int kt = 0; kt < 16; ++kt) {
        short8 av[4];
#pragma unroll
        for (int mt = 0; mt < 4; ++mt) {
            int q = qb + mt * 16 + lrow;
            if (kt < 8) {        // hs, row-major split arrays
                const ushort* src = (kt < 4) ? hs_hi : hs_lo;
                av[mt] = *(const short8*)(src + (size_t)(b * 1024 + q) * 128
                                          + (kt & 3) * 32 + lk * 8);
            } else {             // hidden_intensity
                int ktl = kt - 8;
                const ushort* src = (ktl < 4) ? hi_hi : hi_lo;
                av[mt] = *(const short8*)(src + (size_t)(b * 256 + (q >> 2)) * 128
                                          + (ktl & 3) * 32 + lk * 8);
            }
        }
#pragma unroll
        for (int nt = 0; nt < 2; ++nt) {
            short8 bv = *(const short8*)(wp1 + (size_t)(kt * 8 + w * 2 + nt) * 512 + l * 8);
#pragma unroll
            for (int mt = 0; mt < 4; ++mt)
                acc[mt][nt] = MFMA16(av[mt], bv, acc[mt][nt]);
        }
    }

    // epilogue1: relu + split -> h1 planes (hi: plane w, lo: plane 4+w)
#pragma unroll
    for (int mt = 0; mt < 4; ++mt)
#pragma unroll
        for (int nt = 0; nt < 2; ++nt)
#pragma unroll
            for (int reg = 0; reg < 4; ++reg) {
                float v = fmaxf(acc[mt][nt][reg], 0.0f);
                ushort vh, vl; bsplit(v, vh, vl);
                int s = lk * 4 + reg, jj = nt * 16 + lrow;
                h1f[(w * 4 + mt) * 640 + s * 40 + jj]       = vh;
                h1f[((4 + w) * 4 + mt) * 640 + s * 40 + jj] = vl;
            }
    __syncthreads();

    // ============ GEMM2: h2 = relu(h1 @ W2^T + b2), K'=256, cols 16w.. =======
    f32x4 acc2[4];
    {
        float bias = b2[16 * w + lrow];
#pragma unroll
        for (int mt = 0; mt < 4; ++mt)
            acc2[mt] = (f32x4){bias, bias, bias, bias};
    }
#pragma unroll
    for (int kt = 0; kt < 8; ++kt) {
        short8 bv = *(const short8*)(wp2 + (size_t)(kt * 4 + w) * 512 + l * 8);
#pragma unroll
        for (int mt = 0; mt < 4; ++mt) {
            short8 a = *(const short8*)&h1f[(kt * 4 + mt) * 640 + lrow * 40 + lk * 8];
            acc2[mt] = MFMA16(a, bv, acc2[mt]);
        }
    }
    // epilogue2: relu + split -> h2 planes (hi: col>>5, lo: 2+(col>>5))
#pragma unroll
    for (int mt = 0; mt < 4; ++mt)
#pragma unroll
        for (int reg = 0; reg < 4; ++reg) {
            float v = fmaxf(acc2[mt][reg], 0.0f);
            ushort vh, vl; bsplit(v, vh, vl);
            int s = lk * 4 + reg, jl2 = (w & 1) * 16 + lrow;
            h2f[((w >> 1) * 4 + mt) * 640 + s * 40 + jl2]       = vh;
            h2f[((2 + (w >> 1)) * 4 + mt) * 640 + s * 40 + jl2] = vl;
        }
    __syncthreads();

    // ============ GEMM3: pr = h2 @ W3^T + b3, K'=128; wave w -> rows 16w.. ===
    f32x4 acc3 = (f32x4){0.0f, 0.0f, 0.0f, 0.0f};
#pragma unroll
    for (int kt = 0; kt < 4; ++kt) {
        short8 a  = *(const short8*)&h2f[(kt * 4 + w) * 640 + lrow * 40 + lk * 8];
        short8 bv = *(const short8*)(wp3 + (size_t)kt * 512 + l * 8);
        acc3 = MFMA16(a, bv, acc3);
    }

    // epilogue3: cur(hi/lo) <- pr (raw, split); head: sum relu(pr)*Wf over C, Ct
    const int c = lrow;
    const float b3v = (c < 8) ? b3[c] : 0.0f;
    const float wfv = (c < 8) ? Wf[c] : 0.0f;
    float fr[4];
#pragma unroll
    for (int reg = 0; reg < 4; ++reg) {
        float pr = acc3[reg] + b3v;
        if (c < 8) {
            int row = 16 * w + lk * 4 + reg;
            size_t idx = ((size_t)(b * 1024 + qb + row)) * 8 + c;
            ushort p2h, p2l; bsplit(pr, p2h, p2l);
            cur_hi[idx] = p2h; cur_lo[idx] = p2l;
        }
        fr[reg] = (c < 8) ? fmaxf(pr, 0.0f) * wfv : 0.0f;
    }
#pragma unroll
    for (int reg = 0; reg < 4; ++reg) {
        fr[reg] += __shfl_xor(fr[reg], 1);
        fr[reg] += __shfl_xor(fr[reg], 2);
        fr[reg] += __shfl_xor(fr[reg], 4);
    }
    if ((l & 15) == 0) {
        int n = (qb + 16 * w + lk * 4) >> 2;
        float v = fr[0] + fr[1] + fr[2] + fr[3] + 4.0f * bfp[0];
        out[(size_t)(b * 256 + n) * 4 + jstep] = v;
    }
}

extern "C" void kernel_launch(void* const* d_in, const int* in_sizes, int n_in,
                              void* d_out, int out_size, void* d_ws, size_t ws_size,
                              hipStream_t stream)
{
    const float* x   = (const float*)d_in[0];
    const float* hi  = (const float*)d_in[1];
    const float* r   = (const float*)d_in[2];
    const float* Wih = (const float*)d_in[3];
    const float* Whh = (const float*)d_in[4];
    const float* bih = (const float*)d_in[5];
    const float* bhh = (const float*)d_in[6];
    const float* W1  = (const float*)d_in[7];
    const float* b1  = (const float*)d_in[8];
    const float* W2  = (const float*)d_in[9];
    const float* b2  = (const float*)d_in[10];
    const float* W3  = (const float*)d_in[11];
    const float* b3  = (const float*)d_in[12];
    const float* Wf  = (const float*)d_in[13];
    const float* bf  = (const float*)d_in[14];
    float* out = (float*)d_out;

    ushort* cur_hi = (ushort*)d_ws;                    // 524288
    ushort* cur_lo = cur_hi + 524288;                  // 524288
    ushort* hs_hi  = cur_lo + 524288;                  // 8388608
    ushort* hs_lo  = hs_hi + 8388608;                  // 8388608
    ushort* hi_hi  = hs_lo + 8388608;                  // 2097152
    ushort* hi_lo  = hi_hi + 2097152;                  // 2097152
    ushort* wp1    = hi_lo + 2097152;                  // 65536
    ushort* wp2    = wp1 + 65536;                      // 16384
    ushort* wp3    = wp2 + 16384;                      // 2048
    ushort* wpB    = wp3 + 2048;                       // 147456

    init_cur_k<<<2048, 256, 0, stream>>>(x, cur_hi, cur_lo);
    split_hi_k<<<8192, 256, 0, stream>>>(hi, hi_hi, hi_lo);
    pack_w_k<<<328, 256, 0, stream>>>(W1, W2, W3, wp1, wp2, wp3);
    pack_wB_k<<<576, 256, 0, stream>>>(Whh, Wih, wpB);
    for (int j = 0; j < 4; ++j) {
        lstm_mfma_k<<<256, 512, 0, stream>>>(cur_hi, cur_lo, wpB, bih, bhh,
                                             hs_hi, hs_lo);
        mlp_mfma_k<<<1024, 256, 0, stream>>>(hs_hi, hs_lo, hi_hi, hi_lo, r, j,
                                             wp1, wp2, wp3, W1, b1, b2, b3,
                                             Wf, bf, cur_hi, cur_lo, out);
    }
}

// Round 11
// 449.136 us; speedup vs baseline: 1.3059x; 1.3059x over previous
//
#include <hip/hip_runtime.h>
#include <hip/hip_bf16.h>

// B=64 (LSTM time axis via torch batch_first quirk), L=64 (only col 63 used),
// N=256, C=8, Ct=4 -> NQ=1024 sequences, H=128, 4H=512, RH1=128, RH2=64, S=4.
//
// Split-bf16 scheme (R11 form): h is stored as hi+lo bf16 pair; the LSTM
// recurrent matmul computes (h_hi + h_lo) . W_hi  ==  h . W_hi exactly in
// fp32 accum. Residual error = h . W_lo (~2^-9 relative, SMALLER than the
// R5-R9 scheme, which was silently missing the h_lo.W_hi cross term and
// still passed at 3.9e-3). B-side needs only the W_hi fragments: 20 frags =
// 80 regs per wave instead of 144 -- halves weight traffic / register need.

typedef __attribute__((ext_vector_type(8))) short short8;   // 8 bf16 in 4 VGPRs
typedef __attribute__((ext_vector_type(4))) float f32x4;

#define MFMA16(a, b, c) __builtin_amdgcn_mfma_f32_16x16x32_bf16(a, b, c, 0, 0, 0)

__device__ __forceinline__ float sigf(float x)   { return 1.0f / (1.0f + __expf(-x)); }
__device__ __forceinline__ float tanh_f(float x) { return 1.0f - 2.0f / (__expf(2.0f * x) + 1.0f); }

__device__ __forceinline__ ushort bf16_rne(float v) {
    unsigned u = __float_as_uint(v);
    return (ushort)((u + 0x7FFFu + ((u >> 16) & 1u)) >> 16);
}
__device__ __forceinline__ void bsplit(float v, ushort& h, ushort& l) {
    h = bf16_rne(v);
    float fh = __uint_as_float(((unsigned)h) << 16);
    l = bf16_rne(v - fh);
}

// ---------------- init: cur(hi/lo) <- x[:, 63, :, :] ----------------
__global__ void init_cur_k(const float* __restrict__ x,
                           ushort* __restrict__ cur_hi, ushort* __restrict__ cur_lo)
{
    int i   = blockIdx.x * 256 + threadIdx.x;   // 0 .. 524287
    int b   = i >> 13;
    int rem = i & 8191;
    ushort h, l; bsplit(x[(size_t)b * 524288 + 63 * 8192 + rem], h, l);
    cur_hi[i] = h; cur_lo[i] = l;
}

// ---------------- split hidden_intensity to bf16 hi/lo, once ----------------
__global__ void split_hi_k(const float* __restrict__ hi,
                           ushort* __restrict__ hi_hi, ushort* __restrict__ hi_lo)
{
    int i = blockIdx.x * 256 + threadIdx.x;     // 0 .. 2097151
    ushort h, l; bsplit(hi[i], h, l);
    hi_hi[i] = h; hi_lo[i] = l;
}

// ---------------- pack W1/W2/W3 into stacked-K MFMA B-frags, once ------------
// B-frag (16x16x32): lane l holds B[k = (l>>4)*8 + j][col = l&15], j=0..7.
// (MLP keeps the hi/lo-plane scheme of R5-R9 -- unchanged, passing.)
__global__ void pack_w_k(const float* __restrict__ W1, const float* __restrict__ W2,
                         const float* __restrict__ W3, ushort* __restrict__ wp1,
                         ushort* __restrict__ wp2, ushort* __restrict__ wp3)
{
    int i = blockIdx.x * 256 + threadIdx.x;
    if (i < 65536) {                       // wp1 [kt16][nt8][512]; K'=512 over [hs|hi]
        int fragid = i >> 9, lj = i & 511;
        int kt = fragid >> 3, nt = fragid & 7;
        int l = lj >> 3, j = lj & 7;
        int klocal = (l >> 4) * 8 + j;
        int k = (kt >> 3) * 128 + (kt & 3) * 32 + klocal;   // source k (0..255)
        int hsel = (kt >> 2) & 1;
        int o = nt * 16 + (l & 15);
        ushort h, lo; bsplit(W1[o * 257 + k], h, lo);
        wp1[i] = hsel ? lo : h;
    } else if (i < 65536 + 16384) {        // wp2 [kt8][nt4][512]; K'=256
        int ii = i - 65536;
        int fragid = ii >> 9, lj = ii & 511;
        int kt = fragid >> 2, nt = fragid & 3;
        int l = lj >> 3, j = lj & 7;
        int klocal = (l >> 4) * 8 + j;
        int k = (kt & 3) * 32 + klocal;                     // 0..127
        int hsel = (kt >> 2) & 1;
        int o = nt * 16 + (l & 15);
        ushort h, lo; bsplit(W2[o * 128 + k], h, lo);
        wp2[ii] = hsel ? lo : h;
    } else if (i < 65536 + 16384 + 2048) { // wp3 [kt4][512]; K'=128
        int ii = i - 65536 - 16384;
        int kt = ii >> 9, lj = ii & 511;
        int l = lj >> 3, j = lj & 7;
        int klocal = (l >> 4) * 8 + j;
        int k = (kt & 1) * 32 + klocal;                     // 0..63
        int hsel = kt >> 1;
        int c = l & 15;
        float v = (c < 8) ? W3[c * 64 + k] : 0.0f;
        ushort h, lo; bsplit(v, h, lo);
        wp3[ii] = hsel ? lo : h;
    }
}

// ---------------- pack [W_hh_hi | W_ih_hi] B-frags (hi only), once -----------
// wpB [kt(5)][ntile(32)][512]: kt 0..3 = Whh_hi (K=128); kt 4 = x-plane with
// rows 0-7 AND 8-15 both = Wih_hi (pairs with x_hi and x_lo A-rows), 16-31 = 0.
// col = ntile*16 + (l&15) = gate row 0..511.
__global__ void pack_wB_k(const float* __restrict__ W_hh, const float* __restrict__ W_ih,
                          ushort* __restrict__ wpB)
{
    int i = blockIdx.x * 256 + threadIdx.x;     // 0 .. 81919
    if (i >= 81920) return;
    int frag = i >> 9, lj = i & 511;
    int kt = frag >> 5, ntile = frag & 31;
    int l = lj >> 3, j = lj & 7;
    int klocal = (l >> 4) * 8 + j;              // 0..31
    int col = ntile * 16 + (l & 15);            // gate row 0..511
    float v;
    if (kt < 4) {
        v = W_hh[col * 128 + kt * 32 + klocal];
    } else {
        v = (klocal < 16) ? W_ih[col * 8 + (klocal & 7)] : 0.0f;
    }
    wpB[i] = bf16_rne(v);                       // hi part only
}

// ---------------- LSTM scan: h.W_hi split-bf16 MFMA, 256 blocks -------------
// 256 wgs x 512 thr (8 waves = col-groups). wg owns 4 sequences at M-rows
// {0,4,8,12}. Wave cg computes gate cols g*128 + cg*16 + (l&15), g=0..3.
// C-reg 0 of lane (lk,li) = preact of item (seq=lk, col=cg*16+li).
// A planes kt0-3 = h_hi, kt4-7 = h_lo; both multiply the SAME W_hi frags
// (bw[g][kt&3]) -> (h_hi+h_lo).W_hi = h.W_hi exact. 20 frags = 80 regs,
// pinned to AGPR. hs dump block-coalesced from LDS zone. In-loop barrier
// drains lgkmcnt only (global stores stay in flight).
__global__ __launch_bounds__(512, 2) void lstm_mfma_k(
    const ushort* __restrict__ cur_hi, const ushort* __restrict__ cur_lo,
    const ushort* __restrict__ wpB, const float* __restrict__ b_ih,
    const float* __restrict__ b_hh, ushort* __restrict__ hs_hi,
    ushort* __restrict__ hs_lo)
{
    __shared__ __align__(16) ushort zone[2][8][640];   // 20 KB

    const int t  = threadIdx.x;
    const int cg = t >> 6, l = t & 63;
    const int li = l & 15, lk = l >> 4;
    const int q0 = blockIdx.x * 4;

    // B-frags: 4 gates x 5 planes (4 Whh_hi + 1 x) = 80 regs -> pinned AGPRs
    short8 bw[4][5];
#pragma unroll
    for (int g = 0; g < 4; ++g)
#pragma unroll
        for (int kt = 0; kt < 5; ++kt) {
            bw[g][kt] = *(const short8*)(wpB + (size_t)(kt * 32 + g * 8 + cg) * 512 + l * 8);
            asm volatile("" : "+a"(bw[g][kt]));   // pin to AGPR class, no remat
        }

    float bsum[4];
#pragma unroll
    for (int g = 0; g < 4; ++g) {
        int gc = g * 128 + cg * 16 + li;
        bsum[g] = b_ih[gc] + b_hh[gc];
    }

    for (int i = t; i < 5120; i += 512) ((uint*)zone)[i] = 0;   // both bufs = 0
    float cc = 0.0f;
    __syncthreads();

    const int zp_hi = cg >> 1, zp_lo = 4 + (cg >> 1);
    const int jl    = (cg & 1) * 16 + li;
    const int roff  = li * 40 + lk * 8;       // A-frag read offset in a plane
    const int srow  = lk * 4;                 // this lane's item row (seq lk)

    // branchless per-lane x source: lk=0 -> x_hi, lk=1 -> x_lo, lk>=2 -> any
    // finite garbage (pairs with ZERO rows of the x B-plane -> contributes 0).
    const ushort* xsrc = (lk == 0) ? cur_hi : ((lk == 1) ? cur_lo : cur_hi);
    const size_t  xoff = (size_t)(q0 + (li >> 2)) * 8;

    // coalesced-dump indices: thread t covers 2 ushorts of the 2KB step chunk
    const int dtt  = t & 255;
    const int dseq = dtt >> 6;                 // 0..3
    const int dcol = (dtt << 1) & 127;         // even col
    const int dsel = t >> 8;                   // 0 = hi, 1 = lo
    const ushort* dzsrc0 = &zone[0][(dcol >> 5) + dsel * 4][dseq * 160 + (dcol & 31)];
    const ushort* dzsrc1 = &zone[1][(dcol >> 5) + dsel * 4][dseq * 160 + (dcol & 31)];
    ushort* ddst = (dsel ? hs_lo : hs_hi) + (size_t)(q0 + dseq) * 128 + dcol;

    auto dostep = [&](int step, int p) {
        const int pn = p ^ 1;
        // x A-frag load issued first; L2 latency hides under the LDS reads
        short8 xa = *(const short8*)(xsrc + (size_t)step * 8192 + xoff);

        short8 ah[8];
#pragma unroll
        for (int kt = 0; kt < 8; ++kt)
            ah[kt] = *(const short8*)&zone[p][kt][roff];

        f32x4 acc[4];
#pragma unroll
        for (int g = 0; g < 4; ++g)
            acc[g] = (f32x4){bsum[g], bsum[g], bsum[g], bsum[g]};
#pragma unroll
        for (int kt = 0; kt < 8; ++kt)
#pragma unroll
            for (int g = 0; g < 4; ++g)
                acc[g] = MFMA16(ah[kt], bw[g][kt & 3], acc[g]);   // W_hi reused
#pragma unroll
        for (int g = 0; g < 4; ++g)
            acc[g] = MFMA16(xa, bw[g][4], acc[g]);

        // gate math (torch order i,f,g,o): ONE packed item per lane (reg 0)
        float pi = acc[0][0], pf = acc[1][0], pg = acc[2][0], po = acc[3][0];
        cc = sigf(pf) * cc + sigf(pi) * tanh_f(pg);
        float hv = sigf(po) * tanh_f(cc);
        ushort hh, hl; bsplit(hv, hh, hl);
        zone[pn][zp_hi][srow * 40 + jl] = hh;
        zone[pn][zp_lo][srow * 40 + jl] = hl;
        // drain LDS only; global loads/stores stay in flight
        asm volatile("s_waitcnt lgkmcnt(0)\n\ts_barrier" ::: "memory");

        // block-coalesced dump of zone[pn] (h after this step) -> hs.
        // Reads are covered by the NEXT step's lgkmcnt(0)+barrier, and
        // zone[pn] is not rewritten until step+2. Store is fire-and-forget.
        uint v = *(const uint*)(pn ? dzsrc1 : dzsrc0);
        *(uint*)(ddst + (size_t)step * 131072) = v;
    };

    for (int s2 = 0; s2 < 32; ++s2) {
        dostep(s2 * 2,     0);
        dostep(s2 * 2 + 1, 1);
    }
}

// ---------------- MLP + head for one roll: stacked split-bf16 MFMA ----------
// 1024 wgs (b x 16 q-groups) x 256 thr (4 waves). wg owns 64 items (M=64).
__global__ __launch_bounds__(256, 2) void mlp_mfma_k(
    const ushort* __restrict__ hs_hi, const ushort* __restrict__ hs_lo,
    const ushort* __restrict__ hi_hi, const ushort* __restrict__ hi_lo,
    const float* __restrict__ r, int jstep,
    const ushort* __restrict__ wp1, const ushort* __restrict__ wp2,
    const ushort* __restrict__ wp3,
    const float* __restrict__ W1, const float* __restrict__ b1,
    const float* __restrict__ b2, const float* __restrict__ b3,
    const float* __restrict__ Wf, const float* __restrict__ bfp,
    ushort* __restrict__ cur_hi, ushort* __restrict__ cur_lo,
    float* __restrict__ out)
{
    __shared__ __align__(16) ushort h1f[8 * 4 * 640];   // [plane8][mt4][16x40]  40KB
    __shared__ __align__(16) ushort h2f[4 * 4 * 640];   // [plane4][mt4][16x40]  20KB

    const int t = threadIdx.x;
    const int w = t >> 6, l = t & 63;
    const int lrow = l & 15, lk = l >> 4;
    const int b = blockIdx.x >> 4;
    const int qb = (blockIdx.x & 15) * 64;
    const float rb = r[b * 4 + jstep];

    // ============ GEMM1: h1 = relu([hs|hi|r] @ W1^T + b1), K'=512 ============
    f32x4 acc[4][2];
#pragma unroll
    for (int nt = 0; nt < 2; ++nt) {
        int col = w * 32 + nt * 16 + lrow;
        float bias = b1[col] + rb * W1[col * 257 + 256];   // fold r-col + b1 (fp32)
#pragma unroll
        for (int mt = 0; mt < 4; ++mt)
            acc[mt][nt] = (f32x4){bias, bias, bias, bias};
    }

#pragma unroll 4
    for (int kt = 0; kt < 16; ++kt) {
        short8 av[4];
#pragma unroll
        for (int mt = 0; mt < 4; ++mt) {
            int q = qb + mt * 16 + lrow;
            if (kt < 8) {        // hs, row-major split arrays
                const ushort* src = (kt < 4) ? hs_hi : hs_lo;
                av[mt] = *(const short8*)(src + (size_t)(b * 1024 + q) * 128
                                          + (kt & 3) * 32 + lk * 8);
            } else {             // hidden_intensity
                int ktl = kt - 8;
                const ushort* src = (ktl < 4) ? hi_hi : hi_lo;
                av[mt] = *(const short8*)(src + (size_t)(b * 256 + (q >> 2)) * 128
                                          + (ktl & 3) * 32 + lk * 8);
            }
        }
#pragma unroll
        for (int nt = 0; nt < 2; ++nt) {
            short8 bv = *(const short8*)(wp1 + (size_t)(kt * 8 + w * 2 + nt) * 512 + l * 8);
#pragma unroll
            for (int mt = 0; mt < 4; ++mt)
                acc[mt][nt] = MFMA16(av[mt], bv, acc[mt][nt]);
        }
    }

    // epilogue1: relu + split -> h1 planes (hi: plane w, lo: plane 4+w)
#pragma unroll
    for (int mt = 0; mt < 4; ++mt)
#pragma unroll
        for (int nt = 0; nt < 2; ++nt)
#pragma unroll
            for (int reg = 0; reg < 4; ++reg) {
                float v = fmaxf(acc[mt][nt][reg], 0.0f);
                ushort vh, vl; bsplit(v, vh, vl);
                int s = lk * 4 + reg, jj = nt * 16 + lrow;
                h1f[(w * 4 + mt) * 640 + s * 40 + jj]       = vh;
                h1f[((4 + w) * 4 + mt) * 640 + s * 40 + jj] = vl;
            }
    __syncthreads();

    // ============ GEMM2: h2 = relu(h1 @ W2^T + b2), K'=256, cols 16w.. =======
    f32x4 acc2[4];
    {
        float bias = b2[16 * w + lrow];
#pragma unroll
        for (int mt = 0; mt < 4; ++mt)
            acc2[mt] = (f32x4){bias, bias, bias, bias};
    }
#pragma unroll
    for (int kt = 0; kt < 8; ++kt) {
        short8 bv = *(const short8*)(wp2 + (size_t)(kt * 4 + w) * 512 + l * 8);
#pragma unroll
        for (int mt = 0; mt < 4; ++mt) {
            short8 a = *(const short8*)&h1f[(kt * 4 + mt) * 640 + lrow * 40 + lk * 8];
            acc2[mt] = MFMA16(a, bv, acc2[mt]);
        }
    }
    // epilogue2: relu + split -> h2 planes (hi: col>>5, lo: 2+(col>>5))
#pragma unroll
    for (int mt = 0; mt < 4; ++mt)
#pragma unroll
        for (int reg = 0; reg < 4; ++reg) {
            float v = fmaxf(acc2[mt][reg], 0.0f);
            ushort vh, vl; bsplit(v, vh, vl);
            int s = lk * 4 + reg, jl2 = (w & 1) * 16 + lrow;
            h2f[((w >> 1) * 4 + mt) * 640 + s * 40 + jl2]       = vh;
            h2f[((2 + (w >> 1)) * 4 + mt) * 640 + s * 40 + jl2] = vl;
        }
    __syncthreads();

    // ============ GEMM3: pr = h2 @ W3^T + b3, K'=128; wave w -> rows 16w.. ===
    f32x4 acc3 = (f32x4){0.0f, 0.0f, 0.0f, 0.0f};
#pragma unroll
    for (int kt = 0; kt < 4; ++kt) {
        short8 a  = *(const short8*)&h2f[(kt * 4 + w) * 640 + lrow * 40 + lk * 8];
        short8 bv = *(const short8*)(wp3 + (size_t)kt * 512 + l * 8);
        acc3 = MFMA16(a, bv, acc3);
    }

    // epilogue3: cur(hi/lo) <- pr (raw, split); head: sum relu(pr)*Wf over C, Ct
    const int c = lrow;
    const float b3v = (c < 8) ? b3[c] : 0.0f;
    const float wfv = (c < 8) ? Wf[c] : 0.0f;
    float fr[4];
#pragma unroll
    for (int reg = 0; reg < 4; ++reg) {
        float pr = acc3[reg] + b3v;
        if (c < 8) {
            int row = 16 * w + lk * 4 + reg;
            size_t idx = ((size_t)(b * 1024 + qb + row)) * 8 + c;
            ushort p2h, p2l; bsplit(pr, p2h, p2l);
            cur_hi[idx] = p2h; cur_lo[idx] = p2l;
        }
        fr[reg] = (c < 8) ? fmaxf(pr, 0.0f) * wfv : 0.0f;
    }
#pragma unroll
    for (int reg = 0; reg < 4; ++reg) {
        fr[reg] += __shfl_xor(fr[reg], 1);
        fr[reg] += __shfl_xor(fr[reg], 2);
        fr[reg] += __shfl_xor(fr[reg], 4);
    }
    if ((l & 15) == 0) {
        int n = (qb + 16 * w + lk * 4) >> 2;
        float v = fr[0] + fr[1] + fr[2] + fr[3] + 4.0f * bfp[0];
        out[(size_t)(b * 256 + n) * 4 + jstep] = v;
    }
}

extern "C" void kernel_launch(void* const* d_in, const int* in_sizes, int n_in,
                              void* d_out, int out_size, void* d_ws, size_t ws_size,
                              hipStream_t stream)
{
    const float* x   = (const float*)d_in[0];
    const float* hi  = (const float*)d_in[1];
    const float* r   = (const float*)d_in[2];
    const float* Wih = (const float*)d_in[3];
    const float* Whh = (const float*)d_in[4];
    const float* bih = (const float*)d_in[5];
    const float* bhh = (const float*)d_in[6];
    const float* W1  = (const float*)d_in[7];
    const float* b1  = (const float*)d_in[8];
    const float* W2  = (const float*)d_in[9];
    const float* b2  = (const float*)d_in[10];
    const float* W3  = (const float*)d_in[11];
    const float* b3  = (const float*)d_in[12];
    const float* Wf  = (const float*)d_in[13];
    const float* bf  = (const float*)d_in[14];
    float* out = (float*)d_out;

    ushort* cur_hi = (ushort*)d_ws;                    // 524288
    ushort* cur_lo = cur_hi + 524288;                  // 524288
    ushort* hs_hi  = cur_lo + 524288;                  // 8388608
    ushort* hs_lo  = hs_hi + 8388608;                  // 8388608
    ushort* hi_hi  = hs_lo + 8388608;                  // 2097152
    ushort* hi_lo  = hi_hi + 2097152;                  // 2097152
    ushort* wp1    = hi_lo + 2097152;                  // 65536
    ushort* wp2    = wp1 + 65536;                      // 16384
    ushort* wp3    = wp2 + 16384;                      // 2048
    ushort* wpB    = wp3 + 2048;                       // 81920

    init_cur_k<<<2048, 256, 0, stream>>>(x, cur_hi, cur_lo);
    split_hi_k<<<8192, 256, 0, stream>>>(hi, hi_hi, hi_lo);
    pack_w_k<<<328, 256, 0, stream>>>(W1, W2, W3, wp1, wp2, wp3);
    pack_wB_k<<<320, 256, 0, stream>>>(Whh, Wih, wpB);
    for (int j = 0; j < 4; ++j) {
        lstm_mfma_k<<<256, 512, 0, stream>>>(cur_hi, cur_lo, wpB, bih, bhh,
                                             hs_hi, hs_lo);
        mlp_mfma_k<<<1024, 256, 0, stream>>>(hs_hi, hs_lo, hi_hi, hi_lo, r, j,
                                             wp1, wp2, wp3, W1, b1, b2, b3,
                                             Wf, bf, cur_hi, cur_lo, out);
    }
}

// Round 12
// 448.599 us; speedup vs baseline: 1.3075x; 1.0012x over previous
//
#include <hip/hip_runtime.h>
#include <hip/hip_bf16.h>

// B=64 (LSTM time axis via torch batch_first quirk), L=64 (only col 63 used),
// N=256, C=8, Ct=4 -> NQ=1024 sequences, H=128, 4H=512, RH1=128, RH2=64, S=4.
//
// Split-bf16 scheme: h stored as hi+lo bf16 pair; LSTM recurrent matmul is
// (h_hi + h_lo) . W_hi == h . W_hi exactly (fp32 accum); residual = h . W_lo.
//
// R12: A-fragment LDS reads are BROADCAST - the 16-row M-tile holds only 4
// real sequences (rows 0,4,8,12); pad lanes (li%4 != 0) now read their
// group's real row (roff uses li&12), so the wave presents 16 distinct 16B
// lines instead of 64 -> 4x less LDS bank traffic, same math bit-for-bit
// (pad C rows become copies of real rows; they were ignored anyway).

typedef __attribute__((ext_vector_type(8))) short short8;   // 8 bf16 in 4 VGPRs
typedef __attribute__((ext_vector_type(4))) float f32x4;

#define MFMA16(a, b, c) __builtin_amdgcn_mfma_f32_16x16x32_bf16(a, b, c, 0, 0, 0)

__device__ __forceinline__ float sigf(float x)   { return 1.0f / (1.0f + __expf(-x)); }
__device__ __forceinline__ float tanh_f(float x) { return 1.0f - 2.0f / (__expf(2.0f * x) + 1.0f); }

__device__ __forceinline__ ushort bf16_rne(float v) {
    unsigned u = __float_as_uint(v);
    return (ushort)((u + 0x7FFFu + ((u >> 16) & 1u)) >> 16);
}
__device__ __forceinline__ void bsplit(float v, ushort& h, ushort& l) {
    h = bf16_rne(v);
    float fh = __uint_as_float(((unsigned)h) << 16);
    l = bf16_rne(v - fh);
}

// ---------------- init: cur(hi/lo) <- x[:, 63, :, :] ----------------
__global__ void init_cur_k(const float* __restrict__ x,
                           ushort* __restrict__ cur_hi, ushort* __restrict__ cur_lo)
{
    int i   = blockIdx.x * 256 + threadIdx.x;   // 0 .. 524287
    int b   = i >> 13;
    int rem = i & 8191;
    ushort h, l; bsplit(x[(size_t)b * 524288 + 63 * 8192 + rem], h, l);
    cur_hi[i] = h; cur_lo[i] = l;
}

// ---------------- split hidden_intensity to bf16 hi/lo, once ----------------
__global__ void split_hi_k(const float* __restrict__ hi,
                           ushort* __restrict__ hi_hi, ushort* __restrict__ hi_lo)
{
    int i = blockIdx.x * 256 + threadIdx.x;     // 0 .. 2097151
    ushort h, l; bsplit(hi[i], h, l);
    hi_hi[i] = h; hi_lo[i] = l;
}

// ---------------- pack W1/W2/W3 into stacked-K MFMA B-frags, once ------------
// B-frag (16x16x32): lane l holds B[k = (l>>4)*8 + j][col = l&15], j=0..7.
__global__ void pack_w_k(const float* __restrict__ W1, const float* __restrict__ W2,
                         const float* __restrict__ W3, ushort* __restrict__ wp1,
                         ushort* __restrict__ wp2, ushort* __restrict__ wp3)
{
    int i = blockIdx.x * 256 + threadIdx.x;
    if (i < 65536) {                       // wp1 [kt16][nt8][512]; K'=512 over [hs|hi]
        int fragid = i >> 9, lj = i & 511;
        int kt = fragid >> 3, nt = fragid & 7;
        int l = lj >> 3, j = lj & 7;
        int klocal = (l >> 4) * 8 + j;
        int k = (kt >> 3) * 128 + (kt & 3) * 32 + klocal;   // source k (0..255)
        int hsel = (kt >> 2) & 1;
        int o = nt * 16 + (l & 15);
        ushort h, lo; bsplit(W1[o * 257 + k], h, lo);
        wp1[i] = hsel ? lo : h;
    } else if (i < 65536 + 16384) {        // wp2 [kt8][nt4][512]; K'=256
        int ii = i - 65536;
        int fragid = ii >> 9, lj = ii & 511;
        int kt = fragid >> 2, nt = fragid & 3;
        int l = lj >> 3, j = lj & 7;
        int klocal = (l >> 4) * 8 + j;
        int k = (kt & 3) * 32 + klocal;                     // 0..127
        int hsel = (kt >> 2) & 1;
        int o = nt * 16 + (l & 15);
        ushort h, lo; bsplit(W2[o * 128 + k], h, lo);
        wp2[ii] = hsel ? lo : h;
    } else if (i < 65536 + 16384 + 2048) { // wp3 [kt4][512]; K'=128
        int ii = i - 65536 - 16384;
        int kt = ii >> 9, lj = ii & 511;
        int l = lj >> 3, j = lj & 7;
        int klocal = (l >> 4) * 8 + j;
        int k = (kt & 1) * 32 + klocal;                     // 0..63
        int hsel = kt >> 1;
        int c = l & 15;
        float v = (c < 8) ? W3[c * 64 + k] : 0.0f;
        ushort h, lo; bsplit(v, h, lo);
        wp3[ii] = hsel ? lo : h;
    }
}

// ---------------- pack [W_hh_hi | W_ih_hi] B-frags (hi only), once -----------
// wpB [kt(5)][ntile(32)][512]: kt 0..3 = Whh_hi (K=128); kt 4 = x-plane with
// rows 0-7 AND 8-15 both = Wih_hi (pairs with x_hi and x_lo A-rows), 16-31 = 0.
// col = ntile*16 + (l&15) = gate row 0..511.
__global__ void pack_wB_k(const float* __restrict__ W_hh, const float* __restrict__ W_ih,
                          ushort* __restrict__ wpB)
{
    int i = blockIdx.x * 256 + threadIdx.x;     // 0 .. 81919
    if (i >= 81920) return;
    int frag = i >> 9, lj = i & 511;
    int kt = frag >> 5, ntile = frag & 31;
    int l = lj >> 3, j = lj & 7;
    int klocal = (l >> 4) * 8 + j;              // 0..31
    int col = ntile * 16 + (l & 15);            // gate row 0..511
    float v;
    if (kt < 4) {
        v = W_hh[col * 128 + kt * 32 + klocal];
    } else {
        v = (klocal < 16) ? W_ih[col * 8 + (klocal & 7)] : 0.0f;
    }
    wpB[i] = bf16_rne(v);                       // hi part only
}

// ---------------- LSTM scan: h.W_hi split-bf16 MFMA, 256 blocks -------------
// 256 wgs x 512 thr (8 waves = col-groups). wg owns 4 sequences at M-rows
// {0,4,8,12}. Wave cg computes gate cols g*128 + cg*16 + (l&15), g=0..3.
// C-reg 0 of lane (lk,li) = preact of item (seq=lk, col=cg*16+li).
// A planes kt0-3 = h_hi, kt4-7 = h_lo; both multiply the SAME W_hi frags.
// A-frag LDS reads broadcast per 4-lane group (li&12) -> 4x less LDS traffic.
// hs dump block-coalesced from LDS zone. In-loop barrier drains lgkmcnt only.
__global__ __launch_bounds__(512, 2) void lstm_mfma_k(
    const ushort* __restrict__ cur_hi, const ushort* __restrict__ cur_lo,
    const ushort* __restrict__ wpB, const float* __restrict__ b_ih,
    const float* __restrict__ b_hh, ushort* __restrict__ hs_hi,
    ushort* __restrict__ hs_lo)
{
    __shared__ __align__(16) ushort zone[2][8][640];   // 20 KB

    const int t  = threadIdx.x;
    const int cg = t >> 6, l = t & 63;
    const int li = l & 15, lk = l >> 4;
    const int q0 = blockIdx.x * 4;

    // B-frags: 4 gates x 5 planes (4 Whh_hi + 1 x) = 80 regs -> pinned AGPRs
    short8 bw[4][5];
#pragma unroll
    for (int g = 0; g < 4; ++g)
#pragma unroll
        for (int kt = 0; kt < 5; ++kt) {
            bw[g][kt] = *(const short8*)(wpB + (size_t)(kt * 32 + g * 8 + cg) * 512 + l * 8);
            asm volatile("" : "+a"(bw[g][kt]));   // pin to AGPR class, no remat
        }

    float bsum[4];
#pragma unroll
    for (int g = 0; g < 4; ++g) {
        int gc = g * 128 + cg * 16 + li;
        bsum[g] = b_ih[gc] + b_hh[gc];
    }

    for (int i = t; i < 5120; i += 512) ((uint*)zone)[i] = 0;   // both bufs = 0
    float cc = 0.0f;
    __syncthreads();

    const int zp_hi = cg >> 1, zp_lo = 4 + (cg >> 1);
    const int jl    = (cg & 1) * 16 + li;
    // BROADCAST read offset: pad lanes (li%4 != 0) read their group's real
    // row (li&12). Real rows {0,4,8,12} unchanged -> identical math; 64 lanes
    // present only 16 distinct 16B lines -> LDS serves them as broadcasts.
    const int roff  = (li & 12) * 40 + lk * 8;
    const int srow  = lk * 4;                 // this lane's item row (seq lk)

    // branchless per-lane x source: lk=0 -> x_hi, lk=1 -> x_lo, lk>=2 -> any
    // finite garbage (pairs with ZERO rows of the x B-plane -> contributes 0).
    const ushort* xsrc = (lk == 0) ? cur_hi : ((lk == 1) ? cur_lo : cur_hi);
    const size_t  xoff = (size_t)(q0 + (li >> 2)) * 8;

    // coalesced-dump indices: thread t covers 2 ushorts of the 2KB step chunk
    const int dtt  = t & 255;
    const int dseq = dtt >> 6;                 // 0..3
    const int dcol = (dtt << 1) & 127;         // even col
    const int dsel = t >> 8;                   // 0 = hi, 1 = lo
    const ushort* dzsrc0 = &zone[0][(dcol >> 5) + dsel * 4][dseq * 160 + (dcol & 31)];
    const ushort* dzsrc1 = &zone[1][(dcol >> 5) + dsel * 4][dseq * 160 + (dcol & 31)];
    ushort* ddst = (dsel ? hs_lo : hs_hi) + (size_t)(q0 + dseq) * 128 + dcol;

    auto dostep = [&](int step, int p) {
        const int pn = p ^ 1;
        // x A-frag load issued first; L2 latency hides under the LDS reads
        short8 xa = *(const short8*)(xsrc + (size_t)step * 8192 + xoff);

        short8 ah[8];
#pragma unroll
        for (int kt = 0; kt < 8; ++kt)
            ah[kt] = *(const short8*)&zone[p][kt][roff];

        f32x4 acc[4];
#pragma unroll
        for (int g = 0; g < 4; ++g)
            acc[g] = (f32x4){bsum[g], bsum[g], bsum[g], bsum[g]};
#pragma unroll
        for (int kt = 0; kt < 8; ++kt)
#pragma unroll
            for (int g = 0; g < 4; ++g)
                acc[g] = MFMA16(ah[kt], bw[g][kt & 3], acc[g]);   // W_hi reused
#pragma unroll
        for (int g = 0; g < 4; ++g)
            acc[g] = MFMA16(xa, bw[g][4], acc[g]);

        // gate math (torch order i,f,g,o): ONE packed item per lane (reg 0)
        float pi = acc[0][0], pf = acc[1][0], pg = acc[2][0], po = acc[3][0];
        cc = sigf(pf) * cc + sigf(pi) * tanh_f(pg);
        float hv = sigf(po) * tanh_f(cc);
        ushort hh, hl; bsplit(hv, hh, hl);
        zone[pn][zp_hi][srow * 40 + jl] = hh;
        zone[pn][zp_lo][srow * 40 + jl] = hl;
        // drain LDS only; global loads/stores stay in flight
        asm volatile("s_waitcnt lgkmcnt(0)\n\ts_barrier" ::: "memory");

        // block-coalesced dump of zone[pn] (h after this step) -> hs.
        // Reads are covered by the NEXT step's lgkmcnt(0)+barrier, and
        // zone[pn] is not rewritten until step+2. Store is fire-and-forget.
        uint v = *(const uint*)(pn ? dzsrc1 : dzsrc0);
        *(uint*)(ddst + (size_t)step * 131072) = v;
    };

    for (int s2 = 0; s2 < 32; ++s2) {
        dostep(s2 * 2,     0);
        dostep(s2 * 2 + 1, 1);
    }
}

// ---------------- MLP + head for one roll: stacked split-bf16 MFMA ----------
// 1024 wgs (b x 16 q-groups) x 256 thr (4 waves). wg owns 64 items (M=64).
__global__ __launch_bounds__(256, 2) void mlp_mfma_k(
    const ushort* __restrict__ hs_hi, const ushort* __restrict__ hs_lo,
    const ushort* __restrict__ hi_hi, const ushort* __restrict__ hi_lo,
    const float* __restrict__ r, int jstep,
    const ushort* __restrict__ wp1, const ushort* __restrict__ wp2,
    const ushort* __restrict__ wp3,
    const float* __restrict__ W1, const float* __restrict__ b1,
    const float* __restrict__ b2, const float* __restrict__ b3,
    const float* __restrict__ Wf, const float* __restrict__ bfp,
    ushort* __restrict__ cur_hi, ushort* __restrict__ cur_lo,
    float* __restrict__ out)
{
    __shared__ __align__(16) ushort h1f[8 * 4 * 640];   // [plane8][mt4][16x40]  40KB
    __shared__ __align__(16) ushort h2f[4 * 4 * 640];   // [plane4][mt4][16x40]  20KB

    const int t = threadIdx.x;
    const int w = t >> 6, l = t & 63;
    const int lrow = l & 15, lk = l >> 4;
    const int b = blockIdx.x >> 4;
    const int qb = (blockIdx.x & 15) * 64;
    const float rb = r[b * 4 + jstep];

    // ============ GEMM1: h1 = relu([hs|hi|r] @ W1^T + b1), K'=512 ============
    f32x4 acc[4][2];
#pragma unroll
    for (int nt = 0; nt < 2; ++nt) {
        int col = w * 32 + nt * 16 + lrow;
        float bias = b1[col] + rb * W1[col * 257 + 256];   // fold r-col + b1 (fp32)
#pragma unroll
        for (int mt = 0; mt < 4; ++mt)
            acc[mt][nt] = (f32x4){bias, bias, bias, bias};
    }

#pragma unroll 4
    for (int kt = 0; kt < 16; ++kt) {
        short8 av[4];
#pragma unroll
        for (int mt = 0; mt < 4; ++mt) {
            int q = qb + mt * 16 + lrow;
            if (kt < 8) {        // hs, row-major split arrays
                const ushort* src = (kt < 4) ? hs_hi : hs_lo;
                av[mt] = *(const short8*)(src + (size_t)(b * 1024 + q) * 128
                                          + (kt & 3) * 32 + lk * 8);
            } else {             // hidden_intensity
                int ktl = kt - 8;
                const ushort* src = (ktl < 4) ? hi_hi : hi_lo;
                av[mt] = *(const short8*)(src + (size_t)(b * 256 + (q >> 2)) * 128
                                          + (ktl & 3) * 32 + lk * 8);
            }
        }
#pragma unroll
        for (int nt = 0; nt < 2; ++nt) {
            short8 bv = *(const short8*)(wp1 + (size_t)(kt * 8 + w * 2 + nt) * 512 + l * 8);
#pragma unroll
            for (int mt = 0; mt < 4; ++mt)
                acc[mt][nt] = MFMA16(av[mt], bv, acc[mt][nt]);
        }
    }

    // epilogue1: relu + split -> h1 planes (hi: plane w, lo: plane 4+w)
#pragma unroll
    for (int mt = 0; mt < 4; ++mt)
#pragma unroll
        for (int nt = 0; nt < 2; ++nt)
#pragma unroll
            for (int reg = 0; reg < 4; ++reg) {
                float v = fmaxf(acc[mt][nt][reg], 0.0f);
                ushort vh, vl; bsplit(v, vh, vl);
                int s = lk * 4 + reg, jj = nt * 16 + lrow;
                h1f[(w * 4 + mt) * 640 + s * 40 + jj]       = vh;
                h1f[((4 + w) * 4 + mt) * 640 + s * 40 + jj] = vl;
            }
    __syncthreads();

    // ============ GEMM2: h2 = relu(h1 @ W2^T + b2), K'=256, cols 16w.. =======
    f32x4 acc2[4];
    {
        float bias = b2[16 * w + lrow];
#pragma unroll
        for (int mt = 0; mt < 4; ++mt)
            acc2[mt] = (f32x4){bias, bias, bias, bias};
    }
#pragma unroll
    for (int kt = 0; kt < 8; ++kt) {
        short8 bv = *(const short8*)(wp2 + (size_t)(kt * 4 + w) * 512 + l * 8);
#pragma unroll
        for (int mt = 0; mt < 4; ++mt) {
            short8 a = *(const short8*)&h1f[(kt * 4 + mt) * 640 + lrow * 40 + lk * 8];
            acc2[mt] = MFMA16(a, bv, acc2[mt]);
        }
    }
    // epilogue2: relu + split -> h2 planes (hi: col>>5, lo: 2+(col>>5))
#pragma unroll
    for (int mt = 0; mt < 4; ++mt)
#pragma unroll
        for (int reg = 0; reg < 4; ++reg) {
            float v = fmaxf(acc2[mt][reg], 0.0f);
            ushort vh, vl; bsplit(v, vh, vl);
            int s = lk * 4 + reg, jl2 = (w & 1) * 16 + lrow;
            h2f[((w >> 1) * 4 + mt) * 640 + s * 40 + jl2]       = vh;
            h2f[((2 + (w >> 1)) * 4 + mt) * 640 + s * 40 + jl2] = vl;
        }
    __syncthreads();

    // ============ GEMM3: pr = h2 @ W3^T + b3, K'=128; wave w -> rows 16w.. ===
    f32x4 acc3 = (f32x4){0.0f, 0.0f, 0.0f, 0.0f};
#pragma unroll
    for (int kt = 0; kt < 4; ++kt) {
        short8 a  = *(const short8*)&h2f[(kt * 4 + w) * 640 + lrow * 40 + lk * 8];
        short8 bv = *(const short8*)(wp3 + (size_t)kt * 512 + l * 8);
        acc3 = MFMA16(a, bv, acc3);
    }

    // epilogue3: cur(hi/lo) <- pr (raw, split); head: sum relu(pr)*Wf over C, Ct
    const int c = lrow;
    const float b3v = (c < 8) ? b3[c] : 0.0f;
    const float wfv = (c < 8) ? Wf[c] : 0.0f;
    float fr[4];
#pragma unroll
    for (int reg = 0; reg < 4; ++reg) {
        float pr = acc3[reg] + b3v;
        if (c < 8) {
            int row = 16 * w + lk * 4 + reg;
            size_t idx = ((size_t)(b * 1024 + qb + row)) * 8 + c;
            ushort p2h, p2l; bsplit(pr, p2h, p2l);
            cur_hi[idx] = p2h; cur_lo[idx] = p2l;
        }
        fr[reg] = (c < 8) ? fmaxf(pr, 0.0f) * wfv : 0.0f;
    }
#pragma unroll
    for (int reg = 0; reg < 4; ++reg) {
        fr[reg] += __shfl_xor(fr[reg], 1);
        fr[reg] += __shfl_xor(fr[reg], 2);
        fr[reg] += __shfl_xor(fr[reg], 4);
    }
    if ((l & 15) == 0) {
        int n = (qb + 16 * w + lk * 4) >> 2;
        float v = fr[0] + fr[1] + fr[2] + fr[3] + 4.0f * bfp[0];
        out[(size_t)(b * 256 + n) * 4 + jstep] = v;
    }
}

extern "C" void kernel_launch(void* const* d_in, const int* in_sizes, int n_in,
                              void* d_out, int out_size, void* d_ws, size_t ws_size,
                              hipStream_t stream)
{
    const float* x   = (const float*)d_in[0];
    const float* hi  = (const float*)d_in[1];
    const float* r   = (const float*)d_in[2];
    const float* Wih = (const float*)d_in[3];
    const float* Whh = (const float*)d_in[4];
    const float* bih = (const float*)d_in[5];
    const float* bhh = (const float*)d_in[6];
    const float* W1  = (const float*)d_in[7];
    const float* b1  = (const float*)d_in[8];
    const float* W2  = (const float*)d_in[9];
    const float* b2  = (const float*)d_in[10];
    const float* W3  = (const float*)d_in[11];
    const float* b3  = (const float*)d_in[12];
    const float* Wf  = (const float*)d_in[13];
    const float* bf  = (const float*)d_in[14];
    float* out = (float*)d_out;

    ushort* cur_hi = (ushort*)d_ws;                    // 524288
    ushort* cur_lo = cur_hi + 524288;                  // 524288
    ushort* hs_hi  = cur_lo + 524288;                  // 8388608
    ushort* hs_lo  = hs_hi + 8388608;                  // 8388608
    ushort* hi_hi  = hs_lo + 8388608;                  // 2097152
    ushort* hi_lo  = hi_hi + 2097152;                  // 2097152
    ushort* wp1    = hi_lo + 2097152;                  // 65536
    ushort* wp2    = wp1 + 65536;                      // 16384
    ushort* wp3    = wp2 + 16384;                      // 2048
    ushort* wpB    = wp3 + 2048;                       // 81920

    init_cur_k<<<2048, 256, 0, stream>>>(x, cur_hi, cur_lo);
    split_hi_k<<<8192, 256, 0, stream>>>(hi, hi_hi, hi_lo);
    pack_w_k<<<328, 256, 0, stream>>>(W1, W2, W3, wp1, wp2, wp3);
    pack_wB_k<<<320, 256, 0, stream>>>(Whh, Wih, wpB);
    for (int j = 0; j < 4; ++j) {
        lstm_mfma_k<<<256, 512, 0, stream>>>(cur_hi, cur_lo, wpB, bih, bhh,
                                             hs_hi, hs_lo);
        mlp_mfma_k<<<1024, 256, 0, stream>>>(hs_hi, hs_lo, hi_hi, hi_lo, r, j,
                                             wp1, wp2, wp3, W1, b1, b2, b3,
                                             Wf, bf, cur_hi, cur_lo, out);
    }
}

// Round 13
// 426.963 us; speedup vs baseline: 1.3738x; 1.0507x over previous
//
#include <hip/hip_runtime.h>
#include <hip/hip_bf16.h>

// B=64 (LSTM time axis via torch batch_first quirk), L=64 (only col 63 used),
// N=256, C=8, Ct=4 -> NQ=1024 sequences, H=128, 4H=512, RH1=128, RH2=64, S=4.
//
// Split-bf16 scheme: h stored as hi+lo bf16 pair; LSTM recurrent matmul is
// (h_hi + h_lo) . W_hi == h . W_hi exactly (fp32 accum); residual = h . W_lo.
//
// R13: two latency removals on the step critical path (R12 falsified LDS
// traffic/conflicts as the binding constraint):
//  (a) x A-frag double-buffer prefetch restored (R8 dropped it): the step-N
//      load of x misses L2 (FETCH ~= all of cur from HBM) and stalled the
//      final MFMAs ~500-900 cyc; now loaded one step ahead.
//  (b) hs dump goes straight from gate-math registers (1 global_store_short
//      per array; 32B-contiguous per 16-lane group) - the old LDS round-trip
//      (ds_read + dependent store) cost a ~150 cyc lgkm wait every step.

typedef __attribute__((ext_vector_type(8))) short short8;   // 8 bf16 in 4 VGPRs
typedef __attribute__((ext_vector_type(4))) float f32x4;

#define MFMA16(a, b, c) __builtin_amdgcn_mfma_f32_16x16x32_bf16(a, b, c, 0, 0, 0)

__device__ __forceinline__ float sigf(float x)   { return 1.0f / (1.0f + __expf(-x)); }
__device__ __forceinline__ float tanh_f(float x) { return 1.0f - 2.0f / (__expf(2.0f * x) + 1.0f); }

__device__ __forceinline__ ushort bf16_rne(float v) {
    unsigned u = __float_as_uint(v);
    return (ushort)((u + 0x7FFFu + ((u >> 16) & 1u)) >> 16);
}
__device__ __forceinline__ void bsplit(float v, ushort& h, ushort& l) {
    h = bf16_rne(v);
    float fh = __uint_as_float(((unsigned)h) << 16);
    l = bf16_rne(v - fh);
}

// ---------------- init: cur(hi/lo) <- x[:, 63, :, :] ----------------
__global__ void init_cur_k(const float* __restrict__ x,
                           ushort* __restrict__ cur_hi, ushort* __restrict__ cur_lo)
{
    int i   = blockIdx.x * 256 + threadIdx.x;   // 0 .. 524287
    int b   = i >> 13;
    int rem = i & 8191;
    ushort h, l; bsplit(x[(size_t)b * 524288 + 63 * 8192 + rem], h, l);
    cur_hi[i] = h; cur_lo[i] = l;
}

// ---------------- split hidden_intensity to bf16 hi/lo, once ----------------
__global__ void split_hi_k(const float* __restrict__ hi,
                           ushort* __restrict__ hi_hi, ushort* __restrict__ hi_lo)
{
    int i = blockIdx.x * 256 + threadIdx.x;     // 0 .. 2097151
    ushort h, l; bsplit(hi[i], h, l);
    hi_hi[i] = h; hi_lo[i] = l;
}

// ---------------- pack W1/W2/W3 into stacked-K MFMA B-frags, once ------------
// B-frag (16x16x32): lane l holds B[k = (l>>4)*8 + j][col = l&15], j=0..7.
__global__ void pack_w_k(const float* __restrict__ W1, const float* __restrict__ W2,
                         const float* __restrict__ W3, ushort* __restrict__ wp1,
                         ushort* __restrict__ wp2, ushort* __restrict__ wp3)
{
    int i = blockIdx.x * 256 + threadIdx.x;
    if (i < 65536) {                       // wp1 [kt16][nt8][512]; K'=512 over [hs|hi]
        int fragid = i >> 9, lj = i & 511;
        int kt = fragid >> 3, nt = fragid & 7;
        int l = lj >> 3, j = lj & 7;
        int klocal = (l >> 4) * 8 + j;
        int k = (kt >> 3) * 128 + (kt & 3) * 32 + klocal;   // source k (0..255)
        int hsel = (kt >> 2) & 1;
        int o = nt * 16 + (l & 15);
        ushort h, lo; bsplit(W1[o * 257 + k], h, lo);
        wp1[i] = hsel ? lo : h;
    } else if (i < 65536 + 16384) {        // wp2 [kt8][nt4][512]; K'=256
        int ii = i - 65536;
        int fragid = ii >> 9, lj = ii & 511;
        int kt = fragid >> 2, nt = fragid & 3;
        int l = lj >> 3, j = lj & 7;
        int klocal = (l >> 4) * 8 + j;
        int k = (kt & 3) * 32 + klocal;                     // 0..127
        int hsel = (kt >> 2) & 1;
        int o = nt * 16 + (l & 15);
        ushort h, lo; bsplit(W2[o * 128 + k], h, lo);
        wp2[ii] = hsel ? lo : h;
    } else if (i < 65536 + 16384 + 2048) { // wp3 [kt4][512]; K'=128
        int ii = i - 65536 - 16384;
        int kt = ii >> 9, lj = ii & 511;
        int l = lj >> 3, j = lj & 7;
        int klocal = (l >> 4) * 8 + j;
        int k = (kt & 1) * 32 + klocal;                     // 0..63
        int hsel = kt >> 1;
        int c = l & 15;
        float v = (c < 8) ? W3[c * 64 + k] : 0.0f;
        ushort h, lo; bsplit(v, h, lo);
        wp3[ii] = hsel ? lo : h;
    }
}

// ---------------- pack [W_hh_hi | W_ih_hi] B-frags (hi only), once -----------
// wpB [kt(5)][ntile(32)][512]: kt 0..3 = Whh_hi (K=128); kt 4 = x-plane with
// rows 0-7 AND 8-15 both = Wih_hi (pairs with x_hi and x_lo A-rows), 16-31 = 0.
// col = ntile*16 + (l&15) = gate row 0..511.
__global__ void pack_wB_k(const float* __restrict__ W_hh, const float* __restrict__ W_ih,
                          ushort* __restrict__ wpB)
{
    int i = blockIdx.x * 256 + threadIdx.x;     // 0 .. 81919
    if (i >= 81920) return;
    int frag = i >> 9, lj = i & 511;
    int kt = frag >> 5, ntile = frag & 31;
    int l = lj >> 3, j = lj & 7;
    int klocal = (l >> 4) * 8 + j;              // 0..31
    int col = ntile * 16 + (l & 15);            // gate row 0..511
    float v;
    if (kt < 4) {
        v = W_hh[col * 128 + kt * 32 + klocal];
    } else {
        v = (klocal < 16) ? W_ih[col * 8 + (klocal & 7)] : 0.0f;
    }
    wpB[i] = bf16_rne(v);                       // hi part only
}

// ---------------- LSTM scan: h.W_hi split-bf16 MFMA, 256 blocks -------------
// 256 wgs x 512 thr (8 waves = col-groups). wg owns 4 sequences at M-rows
// {0,4,8,12}. Wave cg computes gate cols g*128 + cg*16 + (l&15), g=0..3.
// C-reg 0 of lane (lk,li) = preact of item (seq=lk, col=cg*16+li).
// A planes kt0-3 = h_hi, kt4-7 = h_lo; both multiply the SAME W_hi frags.
// A-frag LDS reads broadcast per 4-lane group (li&12). x prefetched 1 step
// ahead. hs stored register-direct (no LDS round-trip). In-loop barrier
// drains lgkmcnt only (global loads/stores stay in flight).
__global__ __launch_bounds__(512, 2) void lstm_mfma_k(
    const ushort* __restrict__ cur_hi, const ushort* __restrict__ cur_lo,
    const ushort* __restrict__ wpB, const float* __restrict__ b_ih,
    const float* __restrict__ b_hh, ushort* __restrict__ hs_hi,
    ushort* __restrict__ hs_lo)
{
    __shared__ __align__(16) ushort zone[2][8][640];   // 20 KB

    const int t  = threadIdx.x;
    const int cg = t >> 6, l = t & 63;
    const int li = l & 15, lk = l >> 4;
    const int q0 = blockIdx.x * 4;

    // B-frags: 4 gates x 5 planes (4 Whh_hi + 1 x) = 80 regs -> pinned AGPRs
    short8 bw[4][5];
#pragma unroll
    for (int g = 0; g < 4; ++g)
#pragma unroll
        for (int kt = 0; kt < 5; ++kt) {
            bw[g][kt] = *(const short8*)(wpB + (size_t)(kt * 32 + g * 8 + cg) * 512 + l * 8);
            asm volatile("" : "+a"(bw[g][kt]));   // pin to AGPR class, no remat
        }

    float bsum[4];
#pragma unroll
    for (int g = 0; g < 4; ++g) {
        int gc = g * 128 + cg * 16 + li;
        bsum[g] = b_ih[gc] + b_hh[gc];
    }

    for (int i = t; i < 5120; i += 512) ((uint*)zone)[i] = 0;   // both bufs = 0
    float cc = 0.0f;
    __syncthreads();

    const int zp_hi = cg >> 1, zp_lo = 4 + (cg >> 1);
    const int jl    = (cg & 1) * 16 + li;
    // BROADCAST read offset: pad lanes (li%4 != 0) read their group's real
    // row (li&12); 64 lanes present only 16 distinct 16B lines.
    const int roff  = (li & 12) * 40 + lk * 8;
    const int srow  = lk * 4;                 // this lane's item row (seq lk)

    // branchless per-lane x source: lk=0 -> x_hi, lk=1 -> x_lo, lk>=2 -> any
    // finite garbage (pairs with ZERO rows of the x B-plane -> contributes 0).
    const ushort* xsrc = (lk == 0) ? cur_hi : ((lk == 1) ? cur_lo : cur_hi);
    const size_t  xoff = (size_t)(q0 + (li >> 2)) * 8;

    // register-direct hs store pointers: lane (cg,lk,li) owns
    // hs[seq = q0+lk][col = cg*16+li]; 16-lane groups are 32B-contiguous.
    ushort* ph = hs_hi + (size_t)(q0 + lk) * 128 + cg * 16 + li;
    ushort* pl = hs_lo + (size_t)(q0 + lk) * 128 + cg * 16 + li;

    short8 xaA = *(const short8*)(xsrc + xoff);   // x(step 0)
    short8 xaB;

    auto dostep = [&](int step, int p, short8 xa, short8& xnext) {
        const int pn = p ^ 1;
        // prefetch NEXT step's x: HBM/L2 latency hides under this whole step
        xnext = *(const short8*)(xsrc + (size_t)((step + 1) & 63) * 8192 + xoff);

        short8 ah[8];
#pragma unroll
        for (int kt = 0; kt < 8; ++kt)
            ah[kt] = *(const short8*)&zone[p][kt][roff];

        f32x4 acc[4];
#pragma unroll
        for (int g = 0; g < 4; ++g)
            acc[g] = (f32x4){bsum[g], bsum[g], bsum[g], bsum[g]};
#pragma unroll
        for (int kt = 0; kt < 8; ++kt)
#pragma unroll
            for (int g = 0; g < 4; ++g)
                acc[g] = MFMA16(ah[kt], bw[g][kt & 3], acc[g]);   // W_hi reused
#pragma unroll
        for (int g = 0; g < 4; ++g)
            acc[g] = MFMA16(xa, bw[g][4], acc[g]);

        // gate math (torch order i,f,g,o): ONE packed item per lane (reg 0)
        float pi = acc[0][0], pf = acc[1][0], pg = acc[2][0], po = acc[3][0];
        cc = sigf(pf) * cc + sigf(pi) * tanh_f(pg);
        float hv = sigf(po) * tanh_f(cc);
        ushort hh, hl; bsplit(hv, hh, hl);
        zone[pn][zp_hi][srow * 40 + jl] = hh;
        zone[pn][zp_lo][srow * 40 + jl] = hl;
        // register-direct, fire-and-forget hs stores (no LDS round-trip)
        ph[(size_t)step * 131072] = hh;
        pl[(size_t)step * 131072] = hl;
        // drain LDS only; global loads/stores stay in flight
        asm volatile("s_waitcnt lgkmcnt(0)\n\ts_barrier" ::: "memory");
    };

    for (int s2 = 0; s2 < 32; ++s2) {
        dostep(s2 * 2,     0, xaA, xaB);
        dostep(s2 * 2 + 1, 1, xaB, xaA);
    }
}

// ---------------- MLP + head for one roll: stacked split-bf16 MFMA ----------
// 1024 wgs (b x 16 q-groups) x 256 thr (4 waves). wg owns 64 items (M=64).
__global__ __launch_bounds__(256, 2) void mlp_mfma_k(
    const ushort* __restrict__ hs_hi, const ushort* __restrict__ hs_lo,
    const ushort* __restrict__ hi_hi, const ushort* __restrict__ hi_lo,
    const float* __restrict__ r, int jstep,
    const ushort* __restrict__ wp1, const ushort* __restrict__ wp2,
    const ushort* __restrict__ wp3,
    const float* __restrict__ W1, const float* __restrict__ b1,
    const float* __restrict__ b2, const float* __restrict__ b3,
    const float* __restrict__ Wf, const float* __restrict__ bfp,
    ushort* __restrict__ cur_hi, ushort* __restrict__ cur_lo,
    float* __restrict__ out)
{
    __shared__ __align__(16) ushort h1f[8 * 4 * 640];   // [plane8][mt4][16x40]  40KB
    __shared__ __align__(16) ushort h2f[4 * 4 * 640];   // [plane4][mt4][16x40]  20KB

    const int t = threadIdx.x;
    const int w = t >> 6, l = t & 63;
    const int lrow = l & 15, lk = l >> 4;
    const int b = blockIdx.x >> 4;
    const int qb = (blockIdx.x & 15) * 64;
    const float rb = r[b * 4 + jstep];

    // ============ GEMM1: h1 = relu([hs|hi|r] @ W1^T + b1), K'=512 ============
    f32x4 acc[4][2];
#pragma unroll
    for (int nt = 0; nt < 2; ++nt) {
        int col = w * 32 + nt * 16 + lrow;
        float bias = b1[col] + rb * W1[col * 257 + 256];   // fold r-col + b1 (fp32)
#pragma unroll
        for (int mt = 0; mt < 4; ++mt)
            acc[mt][nt] = (f32x4){bias, bias, bias, bias};
    }

#pragma unroll 4
    for (int kt = 0; kt < 16; ++kt) {
        short8 av[4];
#pragma unroll
        for (int mt = 0; mt < 4; ++mt) {
            int q = qb + mt * 16 + lrow;
            if (kt < 8) {        // hs, row-major split arrays
                const ushort* src = (kt < 4) ? hs_hi : hs_lo;
                av[mt] = *(const short8*)(src + (size_t)(b * 1024 + q) * 128
                                          + (kt & 3) * 32 + lk * 8);
            } else {             // hidden_intensity
                int ktl = kt - 8;
                const ushort* src = (ktl < 4) ? hi_hi : hi_lo;
                av[mt] = *(const short8*)(src + (size_t)(b * 256 + (q >> 2)) * 128
                                          + (ktl & 3) * 32 + lk * 8);
            }
        }
#pragma unroll
        for (int nt = 0; nt < 2; ++nt) {
            short8 bv = *(const short8*)(wp1 + (size_t)(kt * 8 + w * 2 + nt) * 512 + l * 8);
#pragma unroll
            for (int mt = 0; mt < 4; ++mt)
                acc[mt][nt] = MFMA16(av[mt], bv, acc[mt][nt]);
        }
    }

    // epilogue1: relu + split -> h1 planes (hi: plane w, lo: plane 4+w)
#pragma unroll
    for (int mt = 0; mt < 4; ++mt)
#pragma unroll
        for (int nt = 0; nt < 2; ++nt)
#pragma unroll
            for (int reg = 0; reg < 4; ++reg) {
                float v = fmaxf(acc[mt][nt][reg], 0.0f);
                ushort vh, vl; bsplit(v, vh, vl);
                int s = lk * 4 + reg, jj = nt * 16 + lrow;
                h1f[(w * 4 + mt) * 640 + s * 40 + jj]       = vh;
                h1f[((4 + w) * 4 + mt) * 640 + s * 40 + jj] = vl;
            }
    __syncthreads();

    // ============ GEMM2: h2 = relu(h1 @ W2^T + b2), K'=256, cols 16w.. =======
    f32x4 acc2[4];
    {
        float bias = b2[16 * w + lrow];
#pragma unroll
        for (int mt = 0; mt < 4; ++mt)
            acc2[mt] = (f32x4){bias, bias, bias, bias};
    }
#pragma unroll
    for (int kt = 0; kt < 8; ++kt) {
        short8 bv = *(const short8*)(wp2 + (size_t)(kt * 4 + w) * 512 + l * 8);
#pragma unroll
        for (int mt = 0; mt < 4; ++mt) {
            short8 a = *(const short8*)&h1f[(kt * 4 + mt) * 640 + lrow * 40 + lk * 8];
            acc2[mt] = MFMA16(a, bv, acc2[mt]);
        }
    }
    // epilogue2: relu + split -> h2 planes (hi: col>>5, lo: 2+(col>>5))
#pragma unroll
    for (int mt = 0; mt < 4; ++mt)
#pragma unroll
        for (int reg = 0; reg < 4; ++reg) {
            float v = fmaxf(acc2[mt][reg], 0.0f);
            ushort vh, vl; bsplit(v, vh, vl);
            int s = lk * 4 + reg, jl2 = (w & 1) * 16 + lrow;
            h2f[((w >> 1) * 4 + mt) * 640 + s * 40 + jl2]       = vh;
            h2f[((2 + (w >> 1)) * 4 + mt) * 640 + s * 40 + jl2] = vl;
        }
    __syncthreads();

    // ============ GEMM3: pr = h2 @ W3^T + b3, K'=128; wave w -> rows 16w.. ===
    f32x4 acc3 = (f32x4){0.0f, 0.0f, 0.0f, 0.0f};
#pragma unroll
    for (int kt = 0; kt < 4; ++kt) {
        short8 a  = *(const short8*)&h2f[(kt * 4 + w) * 640 + lrow * 40 + lk * 8];
        short8 bv = *(const short8*)(wp3 + (size_t)kt * 512 + l * 8);
        acc3 = MFMA16(a, bv, acc3);
    }

    // epilogue3: cur(hi/lo) <- pr (raw, split); head: sum relu(pr)*Wf over C, Ct
    const int c = lrow;
    const float b3v = (c < 8) ? b3[c] : 0.0f;
    const float wfv = (c < 8) ? Wf[c] : 0.0f;
    float fr[4];
#pragma unroll
    for (int reg = 0; reg < 4; ++reg) {
        float pr = acc3[reg] + b3v;
        if (c < 8) {
            int row = 16 * w + lk * 4 + reg;
            size_t idx = ((size_t)(b * 1024 + qb + row)) * 8 + c;
            ushort p2h, p2l; bsplit(pr, p2h, p2l);
            cur_hi[idx] = p2h; cur_lo[idx] = p2l;
        }
        fr[reg] = (c < 8) ? fmaxf(pr, 0.0f) * wfv : 0.0f;
    }
#pragma unroll
    for (int reg = 0; reg < 4; ++reg) {
        fr[reg] += __shfl_xor(fr[reg], 1);
        fr[reg] += __shfl_xor(fr[reg], 2);
        fr[reg] += __shfl_xor(fr[reg], 4);
    }
    if ((l & 15) == 0) {
        int n = (qb + 16 * w + lk * 4) >> 2;
        float v = fr[0] + fr[1] + fr[2] + fr[3] + 4.0f * bfp[0];
        out[(size_t)(b * 256 + n) * 4 + jstep] = v;
    }
}

extern "C" void kernel_launch(void* const* d_in, const int* in_sizes, int n_in,
                              void* d_out, int out_size, void* d_ws, size_t ws_size,
                              hipStream_t stream)
{
    const float* x   = (const float*)d_in[0];
    const float* hi  = (const float*)d_in[1];
    const float* r   = (const float*)d_in[2];
    const float* Wih = (const float*)d_in[3];
    const float* Whh = (const float*)d_in[4];
    const float* bih = (const float*)d_in[5];
    const float* bhh = (const float*)d_in[6];
    const float* W1  = (const float*)d_in[7];
    const float* b1  = (const float*)d_in[8];
    const float* W2  = (const float*)d_in[9];
    const float* b2  = (const float*)d_in[10];
    const float* W3  = (const float*)d_in[11];
    const float* b3  = (const float*)d_in[12];
    const float* Wf  = (const float*)d_in[13];
    const float* bf  = (const float*)d_in[14];
    float* out = (float*)d_out;

    ushort* cur_hi = (ushort*)d_ws;                    // 524288
    ushort* cur_lo = cur_hi + 524288;                  // 524288
    ushort* hs_hi  = cur_lo + 524288;                  // 8388608
    ushort* hs_lo  = hs_hi + 8388608;                  // 8388608
    ushort* hi_hi  = hs_lo + 8388608;                  // 2097152
    ushort* hi_lo  = hi_hi + 2097152;                  // 2097152
    ushort* wp1    = hi_lo + 2097152;                  // 65536
    ushort* wp2    = wp1 + 65536;                      // 16384
    ushort* wp3    = wp2 + 16384;                      // 2048
    ushort* wpB    = wp3 + 2048;                       // 81920

    init_cur_k<<<2048, 256, 0, stream>>>(x, cur_hi, cur_lo);
    split_hi_k<<<8192, 256, 0, stream>>>(hi, hi_hi, hi_lo);
    pack_w_k<<<328, 256, 0, stream>>>(W1, W2, W3, wp1, wp2, wp3);
    pack_wB_k<<<320, 256, 0, stream>>>(Whh, Wih, wpB);
    for (int j = 0; j < 4; ++j) {
        lstm_mfma_k<<<256, 512, 0, stream>>>(cur_hi, cur_lo, wpB, bih, bhh,
                                             hs_hi, hs_lo);
        mlp_mfma_k<<<1024, 256, 0, stream>>>(hs_hi, hs_lo, hi_hi, hi_lo, r, j,
                                             wp1, wp2, wp3, W1, b1, b2, b3,
                                             Wf, bf, cur_hi, cur_lo, out);
    }
}

// Round 14
// 283.409 us; speedup vs baseline: 2.0696x; 1.5065x over previous
//
#include <hip/hip_runtime.h>
#include <hip/hip_bf16.h>

// B=64 (LSTM time axis via torch batch_first quirk), L=64 (only col 63 used),
// N=256, C=8, Ct=4 -> NQ=1024 sequences, H=128, 4H=512, RH1=128, RH2=64, S=4.
//
// R14: plain-fp16 scheme replaces the bf16 hi/lo split everywhere. fp16 has
// 11 mantissa bits (vs bf16's 8); all tensors here are range-safe (|h|<1,
// |W|<~0.4, x~N(0,1)), so fp16 quantization error (~2^-12 relative) is ~4x
// SMALLER than the passing split scheme's residual. Halves MFMA count,
// chain depth, LDS planes and hs traffic. fp32 accumulation throughout.

typedef __attribute__((ext_vector_type(8))) _Float16 half8;  // 8 f16, 4 VGPRs
typedef __attribute__((ext_vector_type(4))) float f32x4;

#define MFMAH(a, b, c) __builtin_amdgcn_mfma_f32_16x16x32_f16(a, b, c, 0, 0, 0)

__device__ __forceinline__ float sigf(float x)   { return 1.0f / (1.0f + __expf(-x)); }
__device__ __forceinline__ float tanh_f(float x) { return 1.0f - 2.0f / (__expf(2.0f * x) + 1.0f); }

// ---------------- init: cur16 <- fp16(x[:, 63, :, :]) ----------------
__global__ void init_cur_k(const float* __restrict__ x, _Float16* __restrict__ cur16)
{
    int i   = blockIdx.x * 256 + threadIdx.x;   // 0 .. 524287
    int b   = i >> 13;
    int rem = i & 8191;
    cur16[i] = (_Float16)x[(size_t)b * 524288 + 63 * 8192 + rem];
}

// ---------------- hidden_intensity -> fp16, once ----------------
__global__ void cvt_hi_k(const float* __restrict__ hi, _Float16* __restrict__ hi16)
{
    int i = blockIdx.x * 256 + threadIdx.x;     // 0 .. 2097151
    hi16[i] = (_Float16)hi[i];
}

// ---------------- pack W1/W2/W3 into fp16 MFMA B-frags, once ------------
// B-frag (16x16x32): lane l holds B[k = (l>>4)*8 + j][col = l&15], j=0..7.
__global__ void pack_w_k(const float* __restrict__ W1, const float* __restrict__ W2,
                         const float* __restrict__ W3, _Float16* __restrict__ wp1,
                         _Float16* __restrict__ wp2, _Float16* __restrict__ wp3)
{
    int i = blockIdx.x * 256 + threadIdx.x;     // 0 .. 41983
    if (i < 32768) {                       // wp1 [kt8][nt8][512]; K=256 = [hs|hi]
        int fragid = i >> 9, lj = i & 511;
        int kt = fragid >> 3, nt = fragid & 7;
        int l = lj >> 3, j = lj & 7;
        int k = kt * 32 + (l >> 4) * 8 + j;            // 0..255
        int o = nt * 16 + (l & 15);
        wp1[i] = (_Float16)W1[o * 257 + k];
    } else if (i < 32768 + 8192) {         // wp2 [kt4][nt4][512]; K=128
        int ii = i - 32768;
        int fragid = ii >> 9, lj = ii & 511;
        int kt = fragid >> 2, nt = fragid & 3;
        int l = lj >> 3, j = lj & 7;
        int k = kt * 32 + (l >> 4) * 8 + j;            // 0..127
        int o = nt * 16 + (l & 15);
        wp2[ii] = (_Float16)W2[o * 128 + k];
    } else if (i < 32768 + 8192 + 1024) {  // wp3 [kt2][512]; K=64
        int ii = i - 32768 - 8192;
        int kt = ii >> 9, lj = ii & 511;
        int l = lj >> 3, j = lj & 7;
        int k = kt * 32 + (l >> 4) * 8 + j;            // 0..63
        int c = l & 15;
        wp3[ii] = (_Float16)((c < 8) ? W3[c * 64 + k] : 0.0f);
    }
}

// ---------------- pack [W_hh | W_ih] fp16 B-frags, once -----------
// wpB [kt(5)][ntile(32)][512]: kt 0..3 = Whh (K=128); kt 4 = x-plane with
// rows k 0-7 = Wih, rows 8-31 = 0. col = ntile*16 + (l&15) = gate row 0..511.
__global__ void pack_wB_k(const float* __restrict__ W_hh, const float* __restrict__ W_ih,
                          _Float16* __restrict__ wpB)
{
    int i = blockIdx.x * 256 + threadIdx.x;     // 0 .. 81919
    if (i >= 81920) return;
    int frag = i >> 9, lj = i & 511;
    int kt = frag >> 5, ntile = frag & 31;
    int l = lj >> 3, j = lj & 7;
    int klocal = (l >> 4) * 8 + j;              // 0..31
    int col = ntile * 16 + (l & 15);            // gate row 0..511
    float v;
    if (kt < 4)      v = W_hh[col * 128 + kt * 32 + klocal];
    else             v = (klocal < 8) ? W_ih[col * 8 + klocal] : 0.0f;
    wpB[i] = (_Float16)v;
}

// ---------------- LSTM scan: fp16 MFMA, 256 blocks -------------
// 256 wgs x 512 thr (8 waves = col-groups). wg owns 4 sequences at M-rows
// {0,4,8,12}. Wave cg computes gate cols g*128 + cg*16 + (l&15), g=0..3.
// C-reg 0 of lane (lk,li) = preact of item (seq=lk, col=cg*16+li).
// 20 MFMA/wave/step (4 gates x (4 h-planes + 1 x-plane)). x staged in LDS
// once at start -> loop has ZERO global loads. A-frag reads broadcast per
// 4-lane group (li&12). hs stored register-direct fp16. In-loop barrier
// drains lgkmcnt only (global stores stay in flight).
__global__ __launch_bounds__(512, 2) void lstm_mfma_k(
    const _Float16* __restrict__ cur16, const _Float16* __restrict__ wpB,
    const float* __restrict__ b_ih, const float* __restrict__ b_hh,
    _Float16* __restrict__ hs16)
{
    __shared__ __align__(16) _Float16 zone[2][4][640];   // 10 KB h planes
    __shared__ __align__(16) _Float16 xz[64][32];        // 4 KB x slice

    const int t  = threadIdx.x;
    const int cg = t >> 6, l = t & 63;
    const int li = l & 15, lk = l >> 4;
    const int q0 = blockIdx.x * 4;

    // B-frags: 4 gates x 5 planes (4 Whh + 1 x) = 80 regs -> pinned AGPRs
    half8 bw[4][5];
#pragma unroll
    for (int g = 0; g < 4; ++g)
#pragma unroll
        for (int kt = 0; kt < 5; ++kt) {
            bw[g][kt] = *(const half8*)(wpB + (size_t)(kt * 32 + g * 8 + cg) * 512 + l * 8);
            asm volatile("" : "+a"(bw[g][kt]));   // pin to AGPR class, no remat
        }

    float bsum[4];
#pragma unroll
    for (int g = 0; g < 4; ++g) {
        int gc = g * 128 + cg * 16 + li;
        bsum[g] = b_ih[gc] + b_hh[gc];
    }

    for (int i = t; i < 2560; i += 512) ((uint*)zone)[i] = 0;   // both bufs = 0
    // stage this block's entire x slice: 64 steps x 4 seqs x 8 c (fp16) = 4 KB
    if (t < 256) {
        int step = t >> 2, tt = t & 3;
        *(uint4*)&xz[step][tt * 8] =
            *(const uint4*)(cur16 + (size_t)step * 8192 + q0 * 8 + tt * 8);
    }
    float cc = 0.0f;
    __syncthreads();

    const int zpl   = cg >> 1;                // this wave's h plane
    const int jl    = (cg & 1) * 16 + li;
    // BROADCAST read offset: pad lanes (li%4 != 0) read their group's real
    // row (li&12); 64 lanes present only 16 distinct 16B lines.
    const int roff  = (li & 12) * 40 + lk * 8;
    const int srow  = lk * 4;                 // this lane's item row (seq lk)

    // register-direct hs store pointer: lane (cg,lk,li) owns
    // hs[seq = q0+lk][col = cg*16+li]; 16-lane groups are 32B-contiguous.
    _Float16* ph = hs16 + (size_t)(q0 + lk) * 128 + cg * 16 + li;
    // x A-frag LDS address: row li -> seq li>>2 (broadcast); lk>=1 lanes pair
    // with zero B rows, any finite value is fine.
    const _Float16* xrd = &xz[0][(li >> 2) * 8];

    auto dostep = [&](int step, int p) {
        const int pn = p ^ 1;
        half8 xa = *(const half8*)(xrd + step * 32);

        half8 ah[4];
#pragma unroll
        for (int kt = 0; kt < 4; ++kt)
            ah[kt] = *(const half8*)&zone[p][kt][roff];

        f32x4 acc[4];
#pragma unroll
        for (int g = 0; g < 4; ++g)
            acc[g] = (f32x4){bsum[g], bsum[g], bsum[g], bsum[g]};
#pragma unroll
        for (int kt = 0; kt < 4; ++kt)
#pragma unroll
            for (int g = 0; g < 4; ++g)
                acc[g] = MFMAH(ah[kt], bw[g][kt], acc[g]);
#pragma unroll
        for (int g = 0; g < 4; ++g)
            acc[g] = MFMAH(xa, bw[g][4], acc[g]);

        // gate math (torch order i,f,g,o): ONE packed item per lane (reg 0)
        float pi = acc[0][0], pf = acc[1][0], pg = acc[2][0], po = acc[3][0];
        cc = sigf(pf) * cc + sigf(pi) * tanh_f(pg);
        float hv = sigf(po) * tanh_f(cc);
        _Float16 h16 = (_Float16)hv;
        zone[pn][zpl][srow * 40 + jl] = h16;
        // register-direct, fire-and-forget hs store
        ph[(size_t)step * 131072] = h16;
        // drain LDS only; global stores stay in flight
        asm volatile("s_waitcnt lgkmcnt(0)\n\ts_barrier" ::: "memory");
    };

    for (int s2 = 0; s2 < 32; ++s2) {
        dostep(s2 * 2,     0);
        dostep(s2 * 2 + 1, 1);
    }
}

// ---------------- MLP + head for one roll: fp16 MFMA ----------
// 1024 wgs (b x 16 q-groups) x 256 thr (4 waves). wg owns 64 items (M=64).
__global__ __launch_bounds__(256, 2) void mlp_mfma_k(
    const _Float16* __restrict__ hs16, const _Float16* __restrict__ hi16,
    const float* __restrict__ r, int jstep,
    const _Float16* __restrict__ wp1, const _Float16* __restrict__ wp2,
    const _Float16* __restrict__ wp3,
    const float* __restrict__ W1, const float* __restrict__ b1,
    const float* __restrict__ b2, const float* __restrict__ b3,
    const float* __restrict__ Wf, const float* __restrict__ bfp,
    _Float16* __restrict__ cur16, float* __restrict__ out)
{
    __shared__ __align__(16) _Float16 h1f[4 * 4 * 640];   // [plane4][mt4][16x40] 20KB
    __shared__ __align__(16) _Float16 h2f[2 * 4 * 640];   // [plane2][mt4][16x40] 10KB

    const int t = threadIdx.x;
    const int w = t >> 6, l = t & 63;
    const int lrow = l & 15, lk = l >> 4;
    const int b = blockIdx.x >> 4;
    const int qb = (blockIdx.x & 15) * 64;
    const float rb = r[b * 4 + jstep];

    // ============ GEMM1: h1 = relu([hs|hi|r] @ W1^T + b1), K=256 ============
    f32x4 acc[4][2];
#pragma unroll
    for (int nt = 0; nt < 2; ++nt) {
        int col = w * 32 + nt * 16 + lrow;
        float bias = b1[col] + rb * W1[col * 257 + 256];   // fold r-col + b1 (fp32)
#pragma unroll
        for (int mt = 0; mt < 4; ++mt)
            acc[mt][nt] = (f32x4){bias, bias, bias, bias};
    }

#pragma unroll 4
    for (int kt = 0; kt < 8; ++kt) {
        half8 av[4];
#pragma unroll
        for (int mt = 0; mt < 4; ++mt) {
            int q = qb + mt * 16 + lrow;
            if (kt < 4) {        // hs part
                av[mt] = *(const half8*)(hs16 + (size_t)(b * 1024 + q) * 128
                                          + kt * 32 + lk * 8);
            } else {             // hidden_intensity part
                av[mt] = *(const half8*)(hi16 + (size_t)(b * 256 + (q >> 2)) * 128
                                          + (kt - 4) * 32 + lk * 8);
            }
        }
#pragma unroll
        for (int nt = 0; nt < 2; ++nt) {
            half8 bv = *(const half8*)(wp1 + (size_t)(kt * 8 + w * 2 + nt) * 512 + l * 8);
#pragma unroll
            for (int mt = 0; mt < 4; ++mt)
                acc[mt][nt] = MFMAH(av[mt], bv, acc[mt][nt]);
        }
    }

    // epilogue1: relu -> fp16 -> h1 plane w (wave w owns cols w*32..w*32+31)
#pragma unroll
    for (int mt = 0; mt < 4; ++mt)
#pragma unroll
        for (int nt = 0; nt < 2; ++nt)
#pragma unroll
            for (int reg = 0; reg < 4; ++reg) {
                float v = fmaxf(acc[mt][nt][reg], 0.0f);
                int s = lk * 4 + reg, jj = nt * 16 + lrow;
                h1f[(w * 4 + mt) * 640 + s * 40 + jj] = (_Float16)v;
            }
    __syncthreads();

    // ============ GEMM2: h2 = relu(h1 @ W2^T + b2), K=128, cols 16w.. =======
    f32x4 acc2[4];
    {
        float bias = b2[16 * w + lrow];
#pragma unroll
        for (int mt = 0; mt < 4; ++mt)
            acc2[mt] = (f32x4){bias, bias, bias, bias};
    }
#pragma unroll
    for (int kt = 0; kt < 4; ++kt) {
        half8 bv = *(const half8*)(wp2 + (size_t)(kt * 4 + w) * 512 + l * 8);
#pragma unroll
        for (int mt = 0; mt < 4; ++mt) {
            half8 a = *(const half8*)&h1f[(kt * 4 + mt) * 640 + lrow * 40 + lk * 8];
            acc2[mt] = MFMAH(a, bv, acc2[mt]);
        }
    }
    // epilogue2: relu -> fp16 -> h2 plane (col>>5)
#pragma unroll
    for (int mt = 0; mt < 4; ++mt)
#pragma unroll
        for (int reg = 0; reg < 4; ++reg) {
            float v = fmaxf(acc2[mt][reg], 0.0f);
            int s = lk * 4 + reg, jl2 = (w & 1) * 16 + lrow;
            h2f[((w >> 1) * 4 + mt) * 640 + s * 40 + jl2] = (_Float16)v;
        }
    __syncthreads();

    // ============ GEMM3: pr = h2 @ W3^T + b3, K=64; wave w -> rows 16w.. ===
    f32x4 acc3 = (f32x4){0.0f, 0.0f, 0.0f, 0.0f};
#pragma unroll
    for (int kt = 0; kt < 2; ++kt) {
        half8 a  = *(const half8*)&h2f[(kt * 4 + w) * 640 + lrow * 40 + lk * 8];
        half8 bv = *(const half8*)(wp3 + (size_t)kt * 512 + l * 8);
        acc3 = MFMAH(a, bv, acc3);
    }

    // epilogue3: cur16 <- fp16(pr); head: sum relu(pr)*Wf over C, then Ct
    const int c = lrow;
    const float b3v = (c < 8) ? b3[c] : 0.0f;
    const float wfv = (c < 8) ? Wf[c] : 0.0f;
    float fr[4];
#pragma unroll
    for (int reg = 0; reg < 4; ++reg) {
        float pr = acc3[reg] + b3v;
        if (c < 8) {
            int row = 16 * w + lk * 4 + reg;
            cur16[((size_t)(b * 1024 + qb + row)) * 8 + c] = (_Float16)pr;
        }
        fr[reg] = (c < 8) ? fmaxf(pr, 0.0f) * wfv : 0.0f;
    }
#pragma unroll
    for (int reg = 0; reg < 4; ++reg) {
        fr[reg] += __shfl_xor(fr[reg], 1);
        fr[reg] += __shfl_xor(fr[reg], 2);
        fr[reg] += __shfl_xor(fr[reg], 4);
    }
    if ((l & 15) == 0) {
        int n = (qb + 16 * w + lk * 4) >> 2;
        float v = fr[0] + fr[1] + fr[2] + fr[3] + 4.0f * bfp[0];
        out[(size_t)(b * 256 + n) * 4 + jstep] = v;
    }
}

extern "C" void kernel_launch(void* const* d_in, const int* in_sizes, int n_in,
                              void* d_out, int out_size, void* d_ws, size_t ws_size,
                              hipStream_t stream)
{
    const float* x   = (const float*)d_in[0];
    const float* hi  = (const float*)d_in[1];
    const float* r   = (const float*)d_in[2];
    const float* Wih = (const float*)d_in[3];
    const float* Whh = (const float*)d_in[4];
    const float* bih = (const float*)d_in[5];
    const float* bhh = (const float*)d_in[6];
    const float* W1  = (const float*)d_in[7];
    const float* b1  = (const float*)d_in[8];
    const float* W2  = (const float*)d_in[9];
    const float* b2  = (const float*)d_in[10];
    const float* W3  = (const float*)d_in[11];
    const float* b3  = (const float*)d_in[12];
    const float* Wf  = (const float*)d_in[13];
    const float* bf  = (const float*)d_in[14];
    float* out = (float*)d_out;

    _Float16* cur16 = (_Float16*)d_ws;                 // 524288
    _Float16* hs16  = cur16 + 524288;                  // 8388608 (16 MB)
    _Float16* hi16  = hs16 + 8388608;                  // 2097152
    _Float16* wp1   = hi16 + 2097152;                  // 32768
    _Float16* wp2   = wp1 + 32768;                     // 8192
    _Float16* wp3   = wp2 + 8192;                      // 1024
    _Float16* wpB   = wp3 + 1024;                      // 81920

    init_cur_k<<<2048, 256, 0, stream>>>(x, cur16);
    cvt_hi_k<<<8192, 256, 0, stream>>>(hi, hi16);
    pack_w_k<<<164, 256, 0, stream>>>(W1, W2, W3, wp1, wp2, wp3);
    pack_wB_k<<<320, 256, 0, stream>>>(Whh, Wih, wpB);
    for (int j = 0; j < 4; ++j) {
        lstm_mfma_k<<<256, 512, 0, stream>>>(cur16, wpB, bih, bhh, hs16);
        mlp_mfma_k<<<1024, 256, 0, stream>>>(hs16, hi16, r, j, wp1, wp2, wp3,
                                             W1, b1, b2, b3, Wf, bf, cur16, out);
    }
}